// Round 14
// baseline (144.202 us; speedup 1.0000x reference)
//
#include <hip/hip_runtime.h>

typedef _Float16 f16;
typedef _Float16 half8 __attribute__((ext_vector_type(8)));
typedef float floatx4 __attribute__((ext_vector_type(4)));

#define MFMA16(a,b,c) __builtin_amdgcn_mfma_f32_16x16x32_f16((a),(b),(c),0,0,0)
// (1/sqrt(128)) * log2(e)
#define RSL2E 0.12751743f

__device__ __forceinline__ void split2(float x, f16 &h, f16 &l) {
  f16 hh = (f16)x;
  h = hh;
  l = (f16)(x - (float)hh);
}

// ---- LDS staging: rows of 64 halves (128B pitch), XOR-swizzled ----
__device__ __forceinline__ void stage_rows64(const f16* __restrict__ g, int gstride,
                                             f16* lds, int rows, int tid, int nthr) {
  int total = rows * 8;
  for (int idx = tid; idx < total; idx += nthr) {
    int row = idx >> 3, slot = idx & 7;
    float4 v = *(const float4*)(g + (size_t)row * gstride + slot * 8);
    int lofs = ((row << 7) + (slot << 4)) ^ ((row & 7) << 4);
    *(float4*)((char*)lds + lofs) = v;
  }
}
// rows of 128 halves (256B pitch), XOR-swizzled
__device__ __forceinline__ void stage_rows128(const f16* __restrict__ g, int gstride,
                                              f16* lds, int rows, int tid, int nthr) {
  int total = rows * 16;
  for (int idx = tid; idx < total; idx += nthr) {
    int row = idx >> 4, slot = idx & 15;
    float4 v = *(const float4*)(g + (size_t)row * gstride + slot * 8);
    int lofs = ((row << 8) + (slot << 4)) ^ ((row & 7) << 4);
    *(float4*)((char*)lds + lofs) = v;
  }
}
__device__ __forceinline__ half8 fragP128(const f16* lds, int row, int kofs) {
  int ofs = ((row << 7) + (kofs << 1)) ^ ((row & 7) << 4);
  return *(const half8*)((const char*)lds + ofs);
}
__device__ __forceinline__ half8 fragP256(const f16* lds, int row, int kofs) {
  int ofs = ((row << 8) + (kofs << 1)) ^ ((row & 7) << 4);
  return *(const half8*)((const char*)lds + ofs);
}
// pack a float4 into split h/l uint2 pairs
__device__ __forceinline__ void pack_split(float4 v, uint2 &h, uint2 &l) {
  union { f16 a[4]; uint2 u; } hh, ll;
  split2(v.x, hh.a[0], ll.a[0]);
  split2(v.y, hh.a[1], ll.a[1]);
  split2(v.z, hh.a[2], ll.a[2]);
  split2(v.w, hh.a[3], ll.a[3]);
  h = hh.u; l = ll.u;
}

// ---- transpose + split the three weight matrices ----
__global__ void k_splitW(const float* __restrict__ Wq, const float* __restrict__ Wkv,
                         const float* __restrict__ Wo,
                         f16* WqTh, f16* WqTl, f16* WkvTh, f16* WkvTl,
                         f16* WoTh, f16* WoTl) {
  int idx = blockIdx.x * 256 + threadIdx.x;
  if (idx >= 65536) return;
  float v; f16 *ph, *pl; int dst;
  if (idx < 16384) {
    int n = idx >> 7, c = idx & 127;
    v = Wq[c * 128 + n]; ph = WqTh; pl = WqTl; dst = idx;
  } else if (idx < 49152) {
    int t = idx - 16384; int n = t >> 7, c = t & 127;
    v = Wkv[c * 256 + n]; ph = WkvTh; pl = WkvTl; dst = t;
  } else {
    int t = idx - 49152; int n = t >> 7, c = t & 127;
    v = Wo[c * 128 + n]; ph = WoTh; pl = WoTl; dst = t;
  }
  f16 h, l; split2(v, h, l);
  ph[dst] = h; pl[dst] = l;
}

// ---- fused split+GEMM for all three projections in ONE dispatch (grid 768) ----
// with register prefetch of the cc=64 staging inputs (R11 technique)
__global__ __launch_bounds__(512, 2)
void k_proj(const float* __restrict__ query, const float* __restrict__ key_value,
            const f16* __restrict__ WqTh, const f16* __restrict__ WqTl,
            const f16* __restrict__ WkvTh, const f16* __restrict__ WkvTl,
            const float* __restrict__ bq, const float* __restrict__ bkv,
            f16* __restrict__ qhp, f16* __restrict__ khp, f16* __restrict__ vT) {
  int pidx = blockIdx.x >> 8, blk = blockIdx.x & 255;
  const float* A; const f16 *BTh, *BTl; const float* bias; f16* out; int mode;
  if (pidx == 0)      { A = query;     BTh = WqTh;          BTl = WqTl;          bias = bq;        out = qhp; mode = 0; }
  else if (pidx == 1) { A = key_value; BTh = WkvTh;         BTl = WkvTl;         bias = bkv;       out = khp; mode = 0; }
  else                { A = key_value; BTh = WkvTh + 16384; BTl = WkvTl + 16384; bias = bkv + 128; out = vT;  mode = 1; }
  __shared__ f16 pool[24576];
  f16* sAh = pool;           // [64][64]
  f16* sAl = pool + 4096;
  f16* sBh = pool + 8192;    // [128][64]
  f16* sBl = pool + 16384;
  int tid = threadIdx.x, wave = tid >> 6, lane = tid & 63, lg = lane >> 4, lr = lane & 15;
  int wm = wave >> 2, wn = wave & 3;   // 2 x 4 waves, 32x32 wave tiles
  size_t rowbase = (size_t)blk * 64;
  // staging duties
  int arow = tid >> 4, acg = tid & 15;   // A rows arow, arow+32 (fp32, split on write)
  int al0 = ((arow << 7) + (acg << 3)) ^ ((arow & 7) << 4);
  int al1 = (((arow + 32) << 7) + (acg << 3)) ^ ((arow & 7) << 4);
  int brow = tid >> 3, bslot = tid & 7;  // B rows brow, brow+64
  int bl0 = ((brow << 7) + (bslot << 4)) ^ ((brow & 7) << 4);
  int bl1 = (((brow + 64) << 7) + (bslot << 4)) ^ ((brow & 7) << 4);
  const float* Ab = A + rowbase * 128;
  // prefetch cc=0 inputs
  float4 a0 = *(const float4*)(Ab + (size_t)arow * 128 + acg * 4);
  float4 a1 = *(const float4*)(Ab + (size_t)(arow + 32) * 128 + acg * 4);
  float4 b0h = *(const float4*)(BTh + brow * 128 + bslot * 8);
  float4 b1h = *(const float4*)(BTh + (brow + 64) * 128 + bslot * 8);
  float4 b0l = *(const float4*)(BTl + brow * 128 + bslot * 8);
  float4 b1l = *(const float4*)(BTl + (brow + 64) * 128 + bslot * 8);
  floatx4 zero = {0.f, 0.f, 0.f, 0.f};
  floatx4 acc[2][2] = {{zero, zero}, {zero, zero}};
  #pragma unroll
  for (int cc = 0; cc < 128; cc += 64) {
    __syncthreads();
    {
      uint2 h, l;
      pack_split(a0, h, l);
      *(uint2*)((char*)sAh + al0) = h; *(uint2*)((char*)sAl + al0) = l;
      pack_split(a1, h, l);
      *(uint2*)((char*)sAh + al1) = h; *(uint2*)((char*)sAl + al1) = l;
    }
    *(float4*)((char*)sBh + bl0) = b0h;
    *(float4*)((char*)sBh + bl1) = b1h;
    *(float4*)((char*)sBl + bl0) = b0l;
    *(float4*)((char*)sBl + bl1) = b1l;
    __syncthreads();
    if (cc == 0) {   // prefetch cc=64 inputs during compute
      a0 = *(const float4*)(Ab + (size_t)arow * 128 + 64 + acg * 4);
      a1 = *(const float4*)(Ab + (size_t)(arow + 32) * 128 + 64 + acg * 4);
      b0h = *(const float4*)(BTh + 64 + brow * 128 + bslot * 8);
      b1h = *(const float4*)(BTh + 64 + (brow + 64) * 128 + bslot * 8);
      b0l = *(const float4*)(BTl + 64 + brow * 128 + bslot * 8);
      b1l = *(const float4*)(BTl + 64 + (brow + 64) * 128 + bslot * 8);
    }
    #pragma unroll
    for (int kc = 0; kc < 64; kc += 32) {
      half8 ah[2], al[2];
      for (int fm = 0; fm < 2; fm++) {
        ah[fm] = fragP128(sAh, wm * 32 + fm * 16 + lr, kc + lg * 8);
        al[fm] = fragP128(sAl, wm * 32 + fm * 16 + lr, kc + lg * 8);
      }
      for (int fn = 0; fn < 2; fn++) {
        half8 bh = fragP128(sBh, wn * 32 + fn * 16 + lr, kc + lg * 8);
        half8 bl = fragP128(sBl, wn * 32 + fn * 16 + lr, kc + lg * 8);
        for (int fm = 0; fm < 2; fm++) {
          acc[fm][fn] = MFMA16(ah[fm], bh, acc[fm][fn]);
          acc[fm][fn] = MFMA16(ah[fm], bl, acc[fm][fn]);
          acc[fm][fn] = MFMA16(al[fm], bh, acc[fm][fn]);
        }
      }
    }
  }
  __syncthreads();
  f16* e = pool;          // [64][136] padded, single
  for (int fm = 0; fm < 2; fm++) for (int fn = 0; fn < 2; fn++) {
    int n = wn * 32 + fn * 16 + lr;
    float bs = bias[n];
    for (int jj = 0; jj < 4; jj++) {
      int m = wm * 32 + fm * 16 + lg * 4 + jj;
      e[m * 136 + n] = (f16)(acc[fm][fn][jj] + bs);
    }
  }
  __syncthreads();
  if (mode == 0) {
    for (int idx = tid; idx < 1024; idx += 512) {
      int r = idx >> 4, sl = idx & 15;
      *(float4*)(out + (rowbase + r) * 128 + sl * 8) =
          *(const float4*)((const char*)e + r * 272 + sl * 16);
    }
  } else {
    size_t bidx = rowbase >> 13, lofs = rowbase & 8191;
    for (int idx = tid; idx < 1024; idx += 512) {
      int c = idx >> 3, sl = idx & 7;
      union { f16 a[8]; float4 v; } th;
      for (int t = 0; t < 8; t++) th.a[t] = e[(sl * 8 + t) * 136 + c];
      *(float4*)(out + (bidx * 128 + c) * 8192 + lofs + sl * 8) = th.v;
    }
  }
}

// ---- fused reduce+final projection: out fp32 = (P0+P1+P2+P3+U) * WoT^T + bo ----
// with register prefetch of the cc=64 staging inputs
__global__ __launch_bounds__(512, 2)
void k_final(const float* __restrict__ Pbuf, const float* __restrict__ U,
             const f16* __restrict__ BTh, const f16* __restrict__ BTl,
             const float* __restrict__ bias, float* __restrict__ out) {
  __shared__ f16 pool[24576];
  f16* sAh = pool;
  f16* sAl = pool + 4096;
  f16* sBh = pool + 8192;
  f16* sBl = pool + 16384;
  int tid = threadIdx.x, wave = tid >> 6, lane = tid & 63, lg = lane >> 4, lr = lane & 15;
  int wm = wave >> 2, wn = wave & 3;
  size_t rowbase = (size_t)blockIdx.x * 64;
  int b = (int)(rowbase >> 13), r0 = (int)(rowbase & 8191);
  int i = r0 >> 9, st = (r0 >> 6) & 7;
  const float* p0 = Pbuf + ((size_t)(((b * 16 + i) * 8 + st) * 4)) * 8192;
  const float* p1 = p0 + 8192;
  const float* p2 = p0 + 16384;
  const float* p3 = p0 + 24576;
  const float* Ub = U + ((size_t)b * 16 + i) * 128;
  // staging duties
  int arow = tid >> 4, acg = tid & 15;   // A rows arow, arow+32
  int al0 = ((arow << 7) + (acg << 3)) ^ ((arow & 7) << 4);
  int al1 = (((arow + 32) << 7) + (acg << 3)) ^ ((arow & 7) << 4);
  int brow = tid >> 3, bslot = tid & 7;
  int bl0 = ((brow << 7) + (bslot << 4)) ^ ((brow & 7) << 4);
  int bl1 = (((brow + 64) << 7) + (bslot << 4)) ^ ((brow & 7) << 4);
  // prefetch cc=0 inputs
  int c0 = acg * 4;
  float4 r0a0 = *(const float4*)(p0 + arow * 128 + c0);
  float4 r0a1 = *(const float4*)(p1 + arow * 128 + c0);
  float4 r0a2 = *(const float4*)(p2 + arow * 128 + c0);
  float4 r0a3 = *(const float4*)(p3 + arow * 128 + c0);
  float4 r1a0 = *(const float4*)(p0 + (arow + 32) * 128 + c0);
  float4 r1a1 = *(const float4*)(p1 + (arow + 32) * 128 + c0);
  float4 r1a2 = *(const float4*)(p2 + (arow + 32) * 128 + c0);
  float4 r1a3 = *(const float4*)(p3 + (arow + 32) * 128 + c0);
  float4 uu = *(const float4*)(Ub + c0);
  float4 b0h = *(const float4*)(BTh + brow * 128 + bslot * 8);
  float4 b1h = *(const float4*)(BTh + (brow + 64) * 128 + bslot * 8);
  float4 b0l = *(const float4*)(BTl + brow * 128 + bslot * 8);
  float4 b1l = *(const float4*)(BTl + (brow + 64) * 128 + bslot * 8);
  floatx4 zero = {0.f, 0.f, 0.f, 0.f};
  floatx4 acc[2][2] = {{zero, zero}, {zero, zero}};
  #pragma unroll
  for (int cc = 0; cc < 128; cc += 64) {
    __syncthreads();
    {
      float4 s0, s1;
      s0.x = (r0a0.x + r0a1.x) + (r0a2.x + r0a3.x) + uu.x;
      s0.y = (r0a0.y + r0a1.y) + (r0a2.y + r0a3.y) + uu.y;
      s0.z = (r0a0.z + r0a1.z) + (r0a2.z + r0a3.z) + uu.z;
      s0.w = (r0a0.w + r0a1.w) + (r0a2.w + r0a3.w) + uu.w;
      s1.x = (r1a0.x + r1a1.x) + (r1a2.x + r1a3.x) + uu.x;
      s1.y = (r1a0.y + r1a1.y) + (r1a2.y + r1a3.y) + uu.y;
      s1.z = (r1a0.z + r1a1.z) + (r1a2.z + r1a3.z) + uu.z;
      s1.w = (r1a0.w + r1a1.w) + (r1a2.w + r1a3.w) + uu.w;
      uint2 h, l;
      pack_split(s0, h, l);
      *(uint2*)((char*)sAh + al0) = h; *(uint2*)((char*)sAl + al0) = l;
      pack_split(s1, h, l);
      *(uint2*)((char*)sAh + al1) = h; *(uint2*)((char*)sAl + al1) = l;
    }
    *(float4*)((char*)sBh + bl0) = b0h;
    *(float4*)((char*)sBh + bl1) = b1h;
    *(float4*)((char*)sBl + bl0) = b0l;
    *(float4*)((char*)sBl + bl1) = b1l;
    __syncthreads();
    if (cc == 0) {   // prefetch cc=64 inputs during compute
      int c1 = 64 + acg * 4;
      r0a0 = *(const float4*)(p0 + arow * 128 + c1);
      r0a1 = *(const float4*)(p1 + arow * 128 + c1);
      r0a2 = *(const float4*)(p2 + arow * 128 + c1);
      r0a3 = *(const float4*)(p3 + arow * 128 + c1);
      r1a0 = *(const float4*)(p0 + (arow + 32) * 128 + c1);
      r1a1 = *(const float4*)(p1 + (arow + 32) * 128 + c1);
      r1a2 = *(const float4*)(p2 + (arow + 32) * 128 + c1);
      r1a3 = *(const float4*)(p3 + (arow + 32) * 128 + c1);
      uu   = *(const float4*)(Ub + c1);
      b0h = *(const float4*)(BTh + 64 + brow * 128 + bslot * 8);
      b1h = *(const float4*)(BTh + 64 + (brow + 64) * 128 + bslot * 8);
      b0l = *(const float4*)(BTl + 64 + brow * 128 + bslot * 8);
      b1l = *(const float4*)(BTl + 64 + (brow + 64) * 128 + bslot * 8);
    }
    #pragma unroll
    for (int kc = 0; kc < 64; kc += 32) {
      half8 ah[2], al[2];
      for (int fm = 0; fm < 2; fm++) {
        ah[fm] = fragP128(sAh, wm * 32 + fm * 16 + lr, kc + lg * 8);
        al[fm] = fragP128(sAl, wm * 32 + fm * 16 + lr, kc + lg * 8);
      }
      for (int fn = 0; fn < 2; fn++) {
        half8 bh = fragP128(sBh, wn * 32 + fn * 16 + lr, kc + lg * 8);
        half8 bl = fragP128(sBl, wn * 32 + fn * 16 + lr, kc + lg * 8);
        for (int fm = 0; fm < 2; fm++) {
          acc[fm][fn] = MFMA16(ah[fm], bh, acc[fm][fn]);
          acc[fm][fn] = MFMA16(ah[fm], bl, acc[fm][fn]);
          acc[fm][fn] = MFMA16(al[fm], bh, acc[fm][fn]);
        }
      }
    }
  }
  __syncthreads();
  float* ef = (float*)pool;   // [64][132] padded fp32
  for (int fm = 0; fm < 2; fm++) for (int fn = 0; fn < 2; fn++) {
    int n = wn * 32 + fn * 16 + lr;
    float bs = bias[n];
    for (int jj = 0; jj < 4; jj++) {
      int m = wm * 32 + fm * 16 + lg * 4 + jj;
      ef[m * 132 + n] = acc[fm][fn][jj] + bs;
    }
  }
  __syncthreads();
  for (int idx = tid; idx < 2048; idx += 512) {
    int r = idx >> 5, sl = idx & 31;
    *(float4*)(out + (rowbase + r) * 128 + sl * 4) = *(const float4*)(ef + r * 132 + sl * 4);
  }
}

// ---- U[b][i][c] = (1/512) * sum over disallowed k-blocks of their column sums of v ----
__global__ void k_U(const f16* __restrict__ vT, float* __restrict__ U) {
  int b = blockIdx.x >> 7, c = blockIdx.x & 127;
  int tid = threadIdx.x;
  const f16* r = vT + ((size_t)b * 128 + c) * 8192;
  float s = 0.f;
  const float4* r4 = (const float4*)(r + tid * 32);
  for (int t = 0; t < 4; t++) {
    float4 v = r4[t];
    const f16* a = (const f16*)&v;
    for (int u = 0; u < 8; u++) s += (float)a[u];
  }
  __shared__ float part[256];
  __shared__ float bs[16];
  part[tid] = s;
  __syncthreads();
  if (tid < 16) {
    float t = 0.f;
    for (int u = 0; u < 16; u++) t += part[tid * 16 + u];
    bs[tid] = t;
  }
  __syncthreads();
  if (tid < 16) {
    int i = tid;
    float tot = 0.f;
    for (int j = 0; j < 16; j++) tot += bs[j];
    int j0 = i - 2 < 0 ? 0 : i - 2;
    int j1 = i + 2 > 15 ? 15 : i + 2;
    float win = 0.f;
    for (int j = j0; j <= j1; j++) win += bs[j];
    U[((size_t)b * 16 + i) * 128 + c] = (tot - win) * (1.0f / 512.0f);
  }
}

// ---- pass A: Z[b][i][j][d] = sum_s exp2(RSL2E * (k_d . q_s)) ----
// with register prefetch of the next sc-chunk's Q tile
__global__ __launch_bounds__(512, 4)
void k_passA(const f16* __restrict__ kp, const f16* __restrict__ qp,
             float* __restrict__ Z) {
  int bid = blockIdx.x;
  int wg = (bid & 7) * 80 + (bid >> 3);     // XCD-aware bijective swizzle (640 = 8*80)
  int dchunk = wg & 3; int rest = wg >> 2;
  int slot = rest % 5; int rest2 = rest / 5;
  int i = rest2 & 15; int b = rest2 >> 4;
  int j = i - 2 + slot;
  if (j < 0 || j > 15) return;
  __shared__ f16 sK[16384], sQ[16384];  // 64 KiB -> 2 WG/CU
  int tid = threadIdx.x, wave = tid >> 6, lane = tid & 63, lg = lane >> 4, lr = lane & 15;
  int wm = wave >> 1, wn = wave & 1;   // 4 x 2 waves; wave tile 32(d) x 64(s)
  size_t krow = (size_t)b * 8192 + j * 512 + dchunk * 128;
  stage_rows128(kp + krow * 128, 128, sK, 128, tid, 512);
  // Q staging duty: rows qr, qr+32, qr+64, qr+96; 16B slot qsl
  int qr = tid >> 4, qsl = tid & 15;
  int ql0 = ((qr << 8) + (qsl << 4)) ^ ((qr & 7) << 4);
  int ql1 = (((qr + 32) << 8) + (qsl << 4)) ^ ((qr & 7) << 4);
  int ql2 = (((qr + 64) << 8) + (qsl << 4)) ^ ((qr & 7) << 4);
  int ql3 = (((qr + 96) << 8) + (qsl << 4)) ^ ((qr & 7) << 4);
  const f16* qb = qp + ((size_t)b * 8192 + i * 512) * 128;
  // prefetch sc=0 Q tile
  float4 q0 = *(const float4*)(qb + (size_t)(qr      ) * 128 + qsl * 8);
  float4 q1 = *(const float4*)(qb + (size_t)(qr +  32) * 128 + qsl * 8);
  float4 q2 = *(const float4*)(qb + (size_t)(qr +  64) * 128 + qsl * 8);
  float4 q3 = *(const float4*)(qb + (size_t)(qr +  96) * 128 + qsl * 8);
  float zp[2][4] = {{0.f,0.f,0.f,0.f},{0.f,0.f,0.f,0.f}};
  floatx4 zero = {0.f, 0.f, 0.f, 0.f};
  for (int sc = 0; sc < 4; sc++) {
    __syncthreads();                 // prev GEMM reads of sQ done (sc=0: K staged)
    *(float4*)((char*)sQ + ql0) = q0;
    *(float4*)((char*)sQ + ql1) = q1;
    *(float4*)((char*)sQ + ql2) = q2;
    *(float4*)((char*)sQ + ql3) = q3;
    __syncthreads();
    if (sc < 3) {                    // prefetch next chunk during compute
      const f16* qn = qb + (size_t)(sc + 1) * 128 * 128;
      q0 = *(const float4*)(qn + (size_t)(qr      ) * 128 + qsl * 8);
      q1 = *(const float4*)(qn + (size_t)(qr +  32) * 128 + qsl * 8);
      q2 = *(const float4*)(qn + (size_t)(qr +  64) * 128 + qsl * 8);
      q3 = *(const float4*)(qn + (size_t)(qr +  96) * 128 + qsl * 8);
    }
    floatx4 acc[2][4] = {{zero,zero,zero,zero},{zero,zero,zero,zero}};
    for (int kc = 0; kc < 128; kc += 32) {
      half8 ah[2];
      for (int fm = 0; fm < 2; fm++)
        ah[fm] = fragP256(sK, wm * 32 + fm * 16 + lr, kc + lg * 8);
      for (int fn = 0; fn < 4; fn++) {
        half8 bh = fragP256(sQ, wn * 64 + fn * 16 + lr, kc + lg * 8);
        for (int fm = 0; fm < 2; fm++)
          acc[fm][fn] = MFMA16(ah[fm], bh, acc[fm][fn]);
      }
    }
    for (int fm = 0; fm < 2; fm++) for (int fn = 0; fn < 4; fn++)
      for (int jj = 0; jj < 4; jj++)
        zp[fm][jj] += exp2f(acc[fm][fn][jj] * RSL2E);
  }
  // in-wave butterfly over lr (16 s-columns)
  for (int off = 1; off < 16; off <<= 1)
    for (int fm = 0; fm < 2; fm++) for (int jj = 0; jj < 4; jj++)
      zp[fm][jj] += __shfl_xor(zp[fm][jj], off, 64);
  // cross-wave combine of the two wn halves via LDS
  __syncthreads();
  float* sred = (float*)sQ;      // 256 floats
  if (lr == 0) {
    for (int fm = 0; fm < 2; fm++) for (int jj = 0; jj < 4; jj++) {
      int d = wm * 32 + fm * 16 + lg * 4 + jj;
      sred[wn * 128 + d] = zp[fm][jj];
    }
  }
  __syncthreads();
  if (tid < 128) {
    size_t zb = (((size_t)(b * 16 + i) * 16 + j) * 512) + dchunk * 128;
    Z[zb + tid] = sred[tid] + sred[128 + tid];
  }
}

// ---- pass B v5: full-width tiles, 4 barriers/iter, one-iteration lookahead ----
// K/V/Z for j+1 issued during iteration j (land across GEMM2 + next K-write)
__global__ __launch_bounds__(512, 4)
void k_passB(const f16* __restrict__ qp, const f16* __restrict__ kp,
             const f16* __restrict__ vT,
             const float* __restrict__ Z, float* __restrict__ Pbuf) {
  int bid = blockIdx.x;
  int wg = ((bid & 7) << 7) | (bid >> 3);   // XCD-aware bijective swizzle (1024 = 8*128)
  int dq = wg & 3, st = (wg >> 2) & 7, i = (wg >> 5) & 15, b = wg >> 9;
  __shared__ __align__(16) char pool[65536];
  f16* sQ  = (f16*)pool;              // [64 s][128 c], 256B pitch, 16 KB
  f16* sKV = (f16*)(pool + 16384);    // [128][128], 256B pitch, 32 KB: K tile, then V tile
  f16* sE  = (f16*)(pool + 49152);    // [64 s][128 d], 256B pitch, 16 KB
  int tid = threadIdx.x, wave = tid >> 6, lane = tid & 63, lg = lane >> 4, lr = lane & 15;
  int w1m = wave >> 1, w1n = wave & 1;    // GEMM1: 4(d) x 2(s)
  int w2m = wave >> 2, w2n = wave & 3;    // GEMM2: 2(s) x 4(c)
  int srow = tid >> 4, sslot = tid & 15;
  int sl0 = (((srow      ) << 8) + (sslot << 4)) ^ ((srow & 7) << 4);
  int sl1 = (((srow +  32) << 8) + (sslot << 4)) ^ ((srow & 7) << 4);
  int sl2 = (((srow +  64) << 8) + (sslot << 4)) ^ ((srow & 7) << 4);
  int sl3 = (((srow +  96) << 8) + (sslot << 4)) ^ ((srow & 7) << 4);
  size_t qrow = (size_t)b * 8192 + i * 512 + st * 64;
  stage_rows128(qp + qrow * 128, 128, sQ, 64, tid, 512);
  floatx4 zero = {0.f, 0.f, 0.f, 0.f};
  floatx4 acc2[2][2] = {{zero, zero}, {zero, zero}};
  const f16* vbase = vT + (size_t)b * 1048576;
  int j0 = i - 2 < 0 ? 0 : i - 2, j1 = i + 2 > 15 ? 15 : i + 2;
  // prefetch iteration j0's K/V/Z
  const f16* kb0 = kp + ((size_t)b * 8192 + j0 * 512 + dq * 128) * 128;
  float4 k0 = *(const float4*)(kb0 + (size_t)(srow      ) * 128 + sslot * 8);
  float4 k1 = *(const float4*)(kb0 + (size_t)(srow +  32) * 128 + sslot * 8);
  float4 k2 = *(const float4*)(kb0 + (size_t)(srow +  64) * 128 + sslot * 8);
  float4 k3 = *(const float4*)(kb0 + (size_t)(srow +  96) * 128 + sslot * 8);
  const f16* gv0 = vbase + (size_t)j0 * 512 + dq * 128;
  float4 v0 = *(const float4*)(gv0 + (size_t)(srow      ) * 8192 + sslot * 8);
  float4 v1 = *(const float4*)(gv0 + (size_t)(srow +  32) * 8192 + sslot * 8);
  float4 v2 = *(const float4*)(gv0 + (size_t)(srow +  64) * 8192 + sslot * 8);
  float4 v3 = *(const float4*)(gv0 + (size_t)(srow +  96) * 8192 + sslot * 8);
  const float* zp0 = Z + (((size_t)(b * 16 + i) * 16 + j0) * 512) + dq * 128 + w1m * 32 + lg * 4;
  float4 za = *(const float4*)(zp0);
  float4 zb4 = *(const float4*)(zp0 + 16);
  for (int j = j0; j <= j1; j++) {
    // reciprocals from prefetched Z (fm=0 -> ra, fm=1 -> rb)
    float4 ra, rb;
    ra.x = 1.0f / za.x;  ra.y = 1.0f / za.y;  ra.z = 1.0f / za.z;  ra.w = 1.0f / za.w;
    rb.x = 1.0f / zb4.x; rb.y = 1.0f / zb4.y; rb.z = 1.0f / zb4.z; rb.w = 1.0f / zb4.w;
    __syncthreads();                 // B1: prev GEMM2 done reading sKV(V)/sE
    *(float4*)((char*)sKV + sl0) = k0;
    *(float4*)((char*)sKV + sl1) = k1;
    *(float4*)((char*)sKV + sl2) = k2;
    *(float4*)((char*)sKV + sl3) = k3;
    __syncthreads();                 // B2: K tile staged
    floatx4 acc1[2][2] = {{zero, zero}, {zero, zero}};
    #pragma unroll
    for (int kc = 0; kc < 128; kc += 32) {
      half8 ah0 = fragP256(sKV, w1m * 32 + lr, kc + lg * 8);
      half8 ah1 = fragP256(sKV, w1m * 32 + 16 + lr, kc + lg * 8);
      #pragma unroll
      for (int fn = 0; fn < 2; fn++) {
        half8 bq = fragP256(sQ, w1n * 32 + fn * 16 + lr, kc + lg * 8);
        acc1[0][fn] = MFMA16(ah0, bq, acc1[0][fn]);
        acc1[1][fn] = MFMA16(ah1, bq, acc1[1][fn]);
      }
    }
    __syncthreads();                 // B3: GEMM1 reads of sKV done
    // all waves: write E' quadrant (packed 4x f16 -> 8B) + stage V tile
    #pragma unroll
    for (int fm = 0; fm < 2; fm++)
      #pragma unroll
      for (int fn = 0; fn < 2; fn++) {
        int s = w1n * 32 + fn * 16 + lr;
        int d0 = w1m * 32 + fm * 16 + lg * 4;
        union { f16 a[4]; float2 u; } pk;
        pk.a[0] = (f16)(exp2f(acc1[fm][fn][0] * RSL2E) * (fm ? rb.x : ra.x));
        pk.a[1] = (f16)(exp2f(acc1[fm][fn][1] * RSL2E) * (fm ? rb.y : ra.y));
        pk.a[2] = (f16)(exp2f(acc1[fm][fn][2] * RSL2E) * (fm ? rb.z : ra.z));
        pk.a[3] = (f16)(exp2f(acc1[fm][fn][3] * RSL2E) * (fm ? rb.w : ra.w));
        int ofs = ((s << 8) + (d0 << 1)) ^ ((s & 7) << 4);
        *(float2*)((char*)sE + ofs) = pk.u;
      }
    *(float4*)((char*)sKV + sl0) = v0;
    *(float4*)((char*)sKV + sl1) = v1;
    *(float4*)((char*)sKV + sl2) = v2;
    *(float4*)((char*)sKV + sl3) = v3;
    if (j < j1) {                    // prefetch next iteration's K/V/Z
      const f16* nkb = kp + ((size_t)b * 8192 + (j + 1) * 512 + dq * 128) * 128;
      k0 = *(const float4*)(nkb + (size_t)(srow      ) * 128 + sslot * 8);
      k1 = *(const float4*)(nkb + (size_t)(srow +  32) * 128 + sslot * 8);
      k2 = *(const float4*)(nkb + (size_t)(srow +  64) * 128 + sslot * 8);
      k3 = *(const float4*)(nkb + (size_t)(srow +  96) * 128 + sslot * 8);
      const f16* ngv = vbase + (size_t)(j + 1) * 512 + dq * 128;
      v0 = *(const float4*)(ngv + (size_t)(srow      ) * 8192 + sslot * 8);
      v1 = *(const float4*)(ngv + (size_t)(srow +  32) * 8192 + sslot * 8);
      v2 = *(const float4*)(ngv + (size_t)(srow +  64) * 8192 + sslot * 8);
      v3 = *(const float4*)(ngv + (size_t)(srow +  96) * 8192 + sslot * 8);
      const float* nzp = Z + (((size_t)(b * 16 + i) * 16 + (j + 1)) * 512) + dq * 128 + w1m * 32 + lg * 4;
      za = *(const float4*)(nzp);
      zb4 = *(const float4*)(nzp + 16);
    }
    __syncthreads();                 // B4: E + V staged
    #pragma unroll
    for (int kc = 0; kc < 128; kc += 32) {
      half8 ea0 = fragP256(sE, w2m * 32 + lr, kc + lg * 8);
      half8 ea1 = fragP256(sE, w2m * 32 + 16 + lr, kc + lg * 8);
      #pragma unroll
      for (int fn = 0; fn < 2; fn++) {
        half8 bh = fragP256(sKV, w2n * 32 + fn * 16 + lr, kc + lg * 8);
        acc2[0][fn] = MFMA16(ea0, bh, acc2[0][fn]);
        acc2[1][fn] = MFMA16(ea1, bh, acc2[1][fn]);
      }
    }
  }
  // epilogue: write f32 partial to Pbuf via LDS for coalescing (padded stride 132)
  __syncthreads();
  float* ef = (float*)pool;   // [64][132] f32 = 33.8 KB
  for (int fm = 0; fm < 2; fm++) for (int fn = 0; fn < 2; fn++) {
    int c = w2n * 32 + fn * 16 + lr;
    for (int jj = 0; jj < 4; jj++) {
      int s = w2m * 32 + fm * 16 + lg * 4 + jj;
      ef[s * 132 + c] = acc2[fm][fn][jj];
    }
  }
  __syncthreads();
  float* po = Pbuf + ((size_t)((((b * 16 + i) * 8 + st) * 4) + dq)) * 8192;
  for (int idx = tid; idx < 2048; idx += 512) {
    int r = idx >> 5, sl = idx & 31;
    *(float4*)(po + r * 128 + sl * 4) = *(const float4*)(ef + r * 132 + sl * 4);
  }
}

extern "C" void kernel_launch(void* const* d_in, const int* in_sizes, int n_in,
                              void* d_out, int out_size, void* d_ws, size_t ws_size,
                              hipStream_t stream) {
  const float* query     = (const float*)d_in[0];
  const float* key_value = (const float*)d_in[1];
  const float* Wq  = (const float*)d_in[2];
  const float* bq  = (const float*)d_in[3];
  const float* Wkv = (const float*)d_in[4];
  const float* bkv = (const float*)d_in[5];
  const float* Wo  = (const float*)d_in[6];
  const float* bo  = (const float*)d_in[7];
  float* out = (float*)d_out;

  char* ws = (char*)d_ws;
  size_t off = 0;
  auto alloc = [&](size_t bytes) -> char* {
    char* p = ws + off;
    off += (bytes + 255) & ~(size_t)255;
    return p;
  };
  const size_t SZH = (size_t)16384 * 128 * 2;   // one f16 array over all rows
  f16* qhp  = (f16*)alloc(SZH);   // q projected, single f16
  f16* khp  = (f16*)alloc(SZH);   // k projected, single f16
  f16* vT   = (f16*)alloc(SZH);   // v projected, transposed [b][c][l], single f16
  float* Pbuf = (float*)alloc((size_t)1024 * 8192 * 4);   // 33.5 MB partials (4 d-quarters)
  f16* WqTh  = (f16*)alloc(32768); f16* WqTl  = (f16*)alloc(32768);
  f16* WkvTh = (f16*)alloc(65536); f16* WkvTl = (f16*)alloc(65536);
  f16* WoTh  = (f16*)alloc(32768); f16* WoTl  = (f16*)alloc(32768);
  float* Zb = (float*)alloc((size_t)2 * 16 * 16 * 512 * 4);
  float* Ub = (float*)alloc((size_t)2 * 16 * 128 * 4);
  if (off > ws_size) return;   // workspace too small: bail

  k_splitW<<<256, 256, 0, stream>>>(Wq, Wkv, Wo, WqTh, WqTl, WkvTh, WkvTl, WoTh, WoTl);
  k_proj<<<768, 512, 0, stream>>>(query, key_value, WqTh, WqTl, WkvTh, WkvTl,
                                  bq, bkv, qhp, khp, vT);
  k_U<<<256, 256, 0, stream>>>(vT, Ub);
  k_passA<<<640, 512, 0, stream>>>(khp, qhp, Zb);
  k_passB<<<1024, 512, 0, stream>>>(qhp, khp, vT, Zb, Pbuf);
  k_final<<<256, 512, 0, stream>>>(Pbuf, Ub, WoTh, WoTl, bo, out);
}

// Round 15
// 118.907 us; speedup vs baseline: 1.2127x; 1.2127x over previous
//
#include <hip/hip_runtime.h>

typedef _Float16 f16;
typedef _Float16 half8 __attribute__((ext_vector_type(8)));
typedef float floatx4 __attribute__((ext_vector_type(4)));

#define MFMA16(a,b,c) __builtin_amdgcn_mfma_f32_16x16x32_f16((a),(b),(c),0,0,0)
// (1/sqrt(128)) * log2(e)
#define RSL2E 0.12751743f

__device__ __forceinline__ void split2(float x, f16 &h, f16 &l) {
  f16 hh = (f16)x;
  h = hh;
  l = (f16)(x - (float)hh);
}

// ---- LDS staging: rows of 64 halves (128B pitch), XOR-swizzled ----
__device__ __forceinline__ void stage_rows64(const f16* __restrict__ g, int gstride,
                                             f16* lds, int rows, int tid, int nthr) {
  int total = rows * 8;
  for (int idx = tid; idx < total; idx += nthr) {
    int row = idx >> 3, slot = idx & 7;
    float4 v = *(const float4*)(g + (size_t)row * gstride + slot * 8);
    int lofs = ((row << 7) + (slot << 4)) ^ ((row & 7) << 4);
    *(float4*)((char*)lds + lofs) = v;
  }
}
// rows of 128 halves (256B pitch), XOR-swizzled
__device__ __forceinline__ void stage_rows128(const f16* __restrict__ g, int gstride,
                                              f16* lds, int rows, int tid, int nthr) {
  int total = rows * 16;
  for (int idx = tid; idx < total; idx += nthr) {
    int row = idx >> 4, slot = idx & 15;
    float4 v = *(const float4*)(g + (size_t)row * gstride + slot * 8);
    int lofs = ((row << 8) + (slot << 4)) ^ ((row & 7) << 4);
    *(float4*)((char*)lds + lofs) = v;
  }
}
__device__ __forceinline__ half8 fragP128(const f16* lds, int row, int kofs) {
  int ofs = ((row << 7) + (kofs << 1)) ^ ((row & 7) << 4);
  return *(const half8*)((const char*)lds + ofs);
}
__device__ __forceinline__ half8 fragP256(const f16* lds, int row, int kofs) {
  int ofs = ((row << 8) + (kofs << 1)) ^ ((row & 7) << 4);
  return *(const half8*)((const char*)lds + ofs);
}
// pack a float4 into split h/l uint2 pairs
__device__ __forceinline__ void pack_split(float4 v, uint2 &h, uint2 &l) {
  union { f16 a[4]; uint2 u; } hh, ll;
  split2(v.x, hh.a[0], ll.a[0]);
  split2(v.y, hh.a[1], ll.a[1]);
  split2(v.z, hh.a[2], ll.a[2]);
  split2(v.w, hh.a[3], ll.a[3]);
  h = hh.u; l = ll.u;
}

// ---- transpose + split the three weight matrices ----
__global__ void k_splitW(const float* __restrict__ Wq, const float* __restrict__ Wkv,
                         const float* __restrict__ Wo,
                         f16* WqTh, f16* WqTl, f16* WkvTh, f16* WkvTl,
                         f16* WoTh, f16* WoTl) {
  int idx = blockIdx.x * 256 + threadIdx.x;
  if (idx >= 65536) return;
  float v; f16 *ph, *pl; int dst;
  if (idx < 16384) {
    int n = idx >> 7, c = idx & 127;
    v = Wq[c * 128 + n]; ph = WqTh; pl = WqTl; dst = idx;
  } else if (idx < 49152) {
    int t = idx - 16384; int n = t >> 7, c = t & 127;
    v = Wkv[c * 256 + n]; ph = WkvTh; pl = WkvTl; dst = t;
  } else {
    int t = idx - 49152; int n = t >> 7, c = t & 127;
    v = Wo[c * 128 + n]; ph = WoTh; pl = WoTl; dst = t;
  }
  f16 h, l; split2(v, h, l);
  ph[dst] = h; pl[dst] = l;
}

// ---- fused split+GEMM for all three projections in ONE dispatch (grid 768) ----
// with register prefetch of the cc=64 staging inputs (R11 technique)
__global__ __launch_bounds__(512, 2)
void k_proj(const float* __restrict__ query, const float* __restrict__ key_value,
            const f16* __restrict__ WqTh, const f16* __restrict__ WqTl,
            const f16* __restrict__ WkvTh, const f16* __restrict__ WkvTl,
            const float* __restrict__ bq, const float* __restrict__ bkv,
            f16* __restrict__ qhp, f16* __restrict__ khp, f16* __restrict__ vT) {
  int pidx = blockIdx.x >> 8, blk = blockIdx.x & 255;
  const float* A; const f16 *BTh, *BTl; const float* bias; f16* out; int mode;
  if (pidx == 0)      { A = query;     BTh = WqTh;          BTl = WqTl;          bias = bq;        out = qhp; mode = 0; }
  else if (pidx == 1) { A = key_value; BTh = WkvTh;         BTl = WkvTl;         bias = bkv;       out = khp; mode = 0; }
  else                { A = key_value; BTh = WkvTh + 16384; BTl = WkvTl + 16384; bias = bkv + 128; out = vT;  mode = 1; }
  __shared__ f16 pool[24576];
  f16* sAh = pool;           // [64][64]
  f16* sAl = pool + 4096;
  f16* sBh = pool + 8192;    // [128][64]
  f16* sBl = pool + 16384;
  int tid = threadIdx.x, wave = tid >> 6, lane = tid & 63, lg = lane >> 4, lr = lane & 15;
  int wm = wave >> 2, wn = wave & 3;   // 2 x 4 waves, 32x32 wave tiles
  size_t rowbase = (size_t)blk * 64;
  // staging duties
  int arow = tid >> 4, acg = tid & 15;   // A rows arow, arow+32 (fp32, split on write)
  int al0 = ((arow << 7) + (acg << 3)) ^ ((arow & 7) << 4);
  int al1 = (((arow + 32) << 7) + (acg << 3)) ^ ((arow & 7) << 4);
  int brow = tid >> 3, bslot = tid & 7;  // B rows brow, brow+64
  int bl0 = ((brow << 7) + (bslot << 4)) ^ ((brow & 7) << 4);
  int bl1 = (((brow + 64) << 7) + (bslot << 4)) ^ ((brow & 7) << 4);
  const float* Ab = A + rowbase * 128;
  // prefetch cc=0 inputs
  float4 a0 = *(const float4*)(Ab + (size_t)arow * 128 + acg * 4);
  float4 a1 = *(const float4*)(Ab + (size_t)(arow + 32) * 128 + acg * 4);
  float4 b0h = *(const float4*)(BTh + brow * 128 + bslot * 8);
  float4 b1h = *(const float4*)(BTh + (brow + 64) * 128 + bslot * 8);
  float4 b0l = *(const float4*)(BTl + brow * 128 + bslot * 8);
  float4 b1l = *(const float4*)(BTl + (brow + 64) * 128 + bslot * 8);
  floatx4 zero = {0.f, 0.f, 0.f, 0.f};
  floatx4 acc[2][2] = {{zero, zero}, {zero, zero}};
  #pragma unroll
  for (int cc = 0; cc < 128; cc += 64) {
    __syncthreads();
    {
      uint2 h, l;
      pack_split(a0, h, l);
      *(uint2*)((char*)sAh + al0) = h; *(uint2*)((char*)sAl + al0) = l;
      pack_split(a1, h, l);
      *(uint2*)((char*)sAh + al1) = h; *(uint2*)((char*)sAl + al1) = l;
    }
    *(float4*)((char*)sBh + bl0) = b0h;
    *(float4*)((char*)sBh + bl1) = b1h;
    *(float4*)((char*)sBl + bl0) = b0l;
    *(float4*)((char*)sBl + bl1) = b1l;
    __syncthreads();
    if (cc == 0) {   // prefetch cc=64 inputs during compute
      a0 = *(const float4*)(Ab + (size_t)arow * 128 + 64 + acg * 4);
      a1 = *(const float4*)(Ab + (size_t)(arow + 32) * 128 + 64 + acg * 4);
      b0h = *(const float4*)(BTh + 64 + brow * 128 + bslot * 8);
      b1h = *(const float4*)(BTh + 64 + (brow + 64) * 128 + bslot * 8);
      b0l = *(const float4*)(BTl + 64 + brow * 128 + bslot * 8);
      b1l = *(const float4*)(BTl + 64 + (brow + 64) * 128 + bslot * 8);
    }
    #pragma unroll
    for (int kc = 0; kc < 64; kc += 32) {
      half8 ah[2], al[2];
      for (int fm = 0; fm < 2; fm++) {
        ah[fm] = fragP128(sAh, wm * 32 + fm * 16 + lr, kc + lg * 8);
        al[fm] = fragP128(sAl, wm * 32 + fm * 16 + lr, kc + lg * 8);
      }
      for (int fn = 0; fn < 2; fn++) {
        half8 bh = fragP128(sBh, wn * 32 + fn * 16 + lr, kc + lg * 8);
        half8 bl = fragP128(sBl, wn * 32 + fn * 16 + lr, kc + lg * 8);
        for (int fm = 0; fm < 2; fm++) {
          acc[fm][fn] = MFMA16(ah[fm], bh, acc[fm][fn]);
          acc[fm][fn] = MFMA16(ah[fm], bl, acc[fm][fn]);
          acc[fm][fn] = MFMA16(al[fm], bh, acc[fm][fn]);
        }
      }
    }
  }
  __syncthreads();
  f16* e = pool;          // [64][136] padded, single
  for (int fm = 0; fm < 2; fm++) for (int fn = 0; fn < 2; fn++) {
    int n = wn * 32 + fn * 16 + lr;
    float bs = bias[n];
    for (int jj = 0; jj < 4; jj++) {
      int m = wm * 32 + fm * 16 + lg * 4 + jj;
      e[m * 136 + n] = (f16)(acc[fm][fn][jj] + bs);
    }
  }
  __syncthreads();
  if (mode == 0) {
    for (int idx = tid; idx < 1024; idx += 512) {
      int r = idx >> 4, sl = idx & 15;
      *(float4*)(out + (rowbase + r) * 128 + sl * 8) =
          *(const float4*)((const char*)e + r * 272 + sl * 16);
    }
  } else {
    size_t bidx = rowbase >> 13, lofs = rowbase & 8191;
    for (int idx = tid; idx < 1024; idx += 512) {
      int c = idx >> 3, sl = idx & 7;
      union { f16 a[8]; float4 v; } th;
      for (int t = 0; t < 8; t++) th.a[t] = e[(sl * 8 + t) * 136 + c];
      *(float4*)(out + (bidx * 128 + c) * 8192 + lofs + sl * 8) = th.v;
    }
  }
}

// ---- fused reduce+final projection: out fp32 = (P0+P1+P2+P3+U) * WoT^T + bo ----
// with register prefetch of the cc=64 staging inputs
__global__ __launch_bounds__(512, 2)
void k_final(const float* __restrict__ Pbuf, const float* __restrict__ U,
             const f16* __restrict__ BTh, const f16* __restrict__ BTl,
             const float* __restrict__ bias, float* __restrict__ out) {
  __shared__ f16 pool[24576];
  f16* sAh = pool;
  f16* sAl = pool + 4096;
  f16* sBh = pool + 8192;
  f16* sBl = pool + 16384;
  int tid = threadIdx.x, wave = tid >> 6, lane = tid & 63, lg = lane >> 4, lr = lane & 15;
  int wm = wave >> 2, wn = wave & 3;
  size_t rowbase = (size_t)blockIdx.x * 64;
  int b = (int)(rowbase >> 13), r0 = (int)(rowbase & 8191);
  int i = r0 >> 9, st = (r0 >> 6) & 7;
  const float* p0 = Pbuf + ((size_t)(((b * 16 + i) * 8 + st) * 4)) * 8192;
  const float* p1 = p0 + 8192;
  const float* p2 = p0 + 16384;
  const float* p3 = p0 + 24576;
  const float* Ub = U + ((size_t)b * 16 + i) * 128;
  // staging duties
  int arow = tid >> 4, acg = tid & 15;   // A rows arow, arow+32
  int al0 = ((arow << 7) + (acg << 3)) ^ ((arow & 7) << 4);
  int al1 = (((arow + 32) << 7) + (acg << 3)) ^ ((arow & 7) << 4);
  int brow = tid >> 3, bslot = tid & 7;
  int bl0 = ((brow << 7) + (bslot << 4)) ^ ((brow & 7) << 4);
  int bl1 = (((brow + 64) << 7) + (bslot << 4)) ^ ((brow & 7) << 4);
  // prefetch cc=0 inputs
  int c0 = acg * 4;
  float4 r0a0 = *(const float4*)(p0 + arow * 128 + c0);
  float4 r0a1 = *(const float4*)(p1 + arow * 128 + c0);
  float4 r0a2 = *(const float4*)(p2 + arow * 128 + c0);
  float4 r0a3 = *(const float4*)(p3 + arow * 128 + c0);
  float4 r1a0 = *(const float4*)(p0 + (arow + 32) * 128 + c0);
  float4 r1a1 = *(const float4*)(p1 + (arow + 32) * 128 + c0);
  float4 r1a2 = *(const float4*)(p2 + (arow + 32) * 128 + c0);
  float4 r1a3 = *(const float4*)(p3 + (arow + 32) * 128 + c0);
  float4 uu = *(const float4*)(Ub + c0);
  float4 b0h = *(const float4*)(BTh + brow * 128 + bslot * 8);
  float4 b1h = *(const float4*)(BTh + (brow + 64) * 128 + bslot * 8);
  float4 b0l = *(const float4*)(BTl + brow * 128 + bslot * 8);
  float4 b1l = *(const float4*)(BTl + (brow + 64) * 128 + bslot * 8);
  floatx4 zero = {0.f, 0.f, 0.f, 0.f};
  floatx4 acc[2][2] = {{zero, zero}, {zero, zero}};
  #pragma unroll
  for (int cc = 0; cc < 128; cc += 64) {
    __syncthreads();
    {
      float4 s0, s1;
      s0.x = (r0a0.x + r0a1.x) + (r0a2.x + r0a3.x) + uu.x;
      s0.y = (r0a0.y + r0a1.y) + (r0a2.y + r0a3.y) + uu.y;
      s0.z = (r0a0.z + r0a1.z) + (r0a2.z + r0a3.z) + uu.z;
      s0.w = (r0a0.w + r0a1.w) + (r0a2.w + r0a3.w) + uu.w;
      s1.x = (r1a0.x + r1a1.x) + (r1a2.x + r1a3.x) + uu.x;
      s1.y = (r1a0.y + r1a1.y) + (r1a2.y + r1a3.y) + uu.y;
      s1.z = (r1a0.z + r1a1.z) + (r1a2.z + r1a3.z) + uu.z;
      s1.w = (r1a0.w + r1a1.w) + (r1a2.w + r1a3.w) + uu.w;
      uint2 h, l;
      pack_split(s0, h, l);
      *(uint2*)((char*)sAh + al0) = h; *(uint2*)((char*)sAl + al0) = l;
      pack_split(s1, h, l);
      *(uint2*)((char*)sAh + al1) = h; *(uint2*)((char*)sAl + al1) = l;
    }
    *(float4*)((char*)sBh + bl0) = b0h;
    *(float4*)((char*)sBh + bl1) = b1h;
    *(float4*)((char*)sBl + bl0) = b0l;
    *(float4*)((char*)sBl + bl1) = b1l;
    __syncthreads();
    if (cc == 0) {   // prefetch cc=64 inputs during compute
      int c1 = 64 + acg * 4;
      r0a0 = *(const float4*)(p0 + arow * 128 + c1);
      r0a1 = *(const float4*)(p1 + arow * 128 + c1);
      r0a2 = *(const float4*)(p2 + arow * 128 + c1);
      r0a3 = *(const float4*)(p3 + arow * 128 + c1);
      r1a0 = *(const float4*)(p0 + (arow + 32) * 128 + c1);
      r1a1 = *(const float4*)(p1 + (arow + 32) * 128 + c1);
      r1a2 = *(const float4*)(p2 + (arow + 32) * 128 + c1);
      r1a3 = *(const float4*)(p3 + (arow + 32) * 128 + c1);
      uu   = *(const float4*)(Ub + c1);
      b0h = *(const float4*)(BTh + 64 + brow * 128 + bslot * 8);
      b1h = *(const float4*)(BTh + 64 + (brow + 64) * 128 + bslot * 8);
      b0l = *(const float4*)(BTl + 64 + brow * 128 + bslot * 8);
      b1l = *(const float4*)(BTl + 64 + (brow + 64) * 128 + bslot * 8);
    }
    #pragma unroll
    for (int kc = 0; kc < 64; kc += 32) {
      half8 ah[2], al[2];
      for (int fm = 0; fm < 2; fm++) {
        ah[fm] = fragP128(sAh, wm * 32 + fm * 16 + lr, kc + lg * 8);
        al[fm] = fragP128(sAl, wm * 32 + fm * 16 + lr, kc + lg * 8);
      }
      for (int fn = 0; fn < 2; fn++) {
        half8 bh = fragP128(sBh, wn * 32 + fn * 16 + lr, kc + lg * 8);
        half8 bl = fragP128(sBl, wn * 32 + fn * 16 + lr, kc + lg * 8);
        for (int fm = 0; fm < 2; fm++) {
          acc[fm][fn] = MFMA16(ah[fm], bh, acc[fm][fn]);
          acc[fm][fn] = MFMA16(ah[fm], bl, acc[fm][fn]);
          acc[fm][fn] = MFMA16(al[fm], bh, acc[fm][fn]);
        }
      }
    }
  }
  __syncthreads();
  float* ef = (float*)pool;   // [64][132] padded fp32
  for (int fm = 0; fm < 2; fm++) for (int fn = 0; fn < 2; fn++) {
    int n = wn * 32 + fn * 16 + lr;
    float bs = bias[n];
    for (int jj = 0; jj < 4; jj++) {
      int m = wm * 32 + fm * 16 + lg * 4 + jj;
      ef[m * 132 + n] = acc[fm][fn][jj] + bs;
    }
  }
  __syncthreads();
  for (int idx = tid; idx < 2048; idx += 512) {
    int r = idx >> 5, sl = idx & 31;
    *(float4*)(out + (rowbase + r) * 128 + sl * 4) = *(const float4*)(ef + r * 132 + sl * 4);
  }
}

// ---- U[b][i][c] = (1/512) * sum over disallowed k-blocks of their column sums of v ----
__global__ void k_U(const f16* __restrict__ vT, float* __restrict__ U) {
  int b = blockIdx.x >> 7, c = blockIdx.x & 127;
  int tid = threadIdx.x;
  const f16* r = vT + ((size_t)b * 128 + c) * 8192;
  float s = 0.f;
  const float4* r4 = (const float4*)(r + tid * 32);
  for (int t = 0; t < 4; t++) {
    float4 v = r4[t];
    const f16* a = (const f16*)&v;
    for (int u = 0; u < 8; u++) s += (float)a[u];
  }
  __shared__ float part[256];
  __shared__ float bs[16];
  part[tid] = s;
  __syncthreads();
  if (tid < 16) {
    float t = 0.f;
    for (int u = 0; u < 16; u++) t += part[tid * 16 + u];
    bs[tid] = t;
  }
  __syncthreads();
  if (tid < 16) {
    int i = tid;
    float tot = 0.f;
    for (int j = 0; j < 16; j++) tot += bs[j];
    int j0 = i - 2 < 0 ? 0 : i - 2;
    int j1 = i + 2 > 15 ? 15 : i + 2;
    float win = 0.f;
    for (int j = j0; j <= j1; j++) win += bs[j];
    U[((size_t)b * 16 + i) * 128 + c] = (tot - win) * (1.0f / 512.0f);
  }
}

// ---- pass A: Z[b][i][j][d] = sum_s exp2(RSL2E * (k_d . q_s)) ----
// with register prefetch of the next sc-chunk's Q tile
__global__ __launch_bounds__(512, 4)
void k_passA(const f16* __restrict__ kp, const f16* __restrict__ qp,
             float* __restrict__ Z) {
  int bid = blockIdx.x;
  int wg = (bid & 7) * 80 + (bid >> 3);     // XCD-aware bijective swizzle (640 = 8*80)
  int dchunk = wg & 3; int rest = wg >> 2;
  int slot = rest % 5; int rest2 = rest / 5;
  int i = rest2 & 15; int b = rest2 >> 4;
  int j = i - 2 + slot;
  if (j < 0 || j > 15) return;
  __shared__ f16 sK[16384], sQ[16384];  // 64 KiB -> 2 WG/CU
  int tid = threadIdx.x, wave = tid >> 6, lane = tid & 63, lg = lane >> 4, lr = lane & 15;
  int wm = wave >> 1, wn = wave & 1;   // 4 x 2 waves; wave tile 32(d) x 64(s)
  size_t krow = (size_t)b * 8192 + j * 512 + dchunk * 128;
  stage_rows128(kp + krow * 128, 128, sK, 128, tid, 512);
  // Q staging duty: rows qr, qr+32, qr+64, qr+96; 16B slot qsl
  int qr = tid >> 4, qsl = tid & 15;
  int ql0 = ((qr << 8) + (qsl << 4)) ^ ((qr & 7) << 4);
  int ql1 = (((qr + 32) << 8) + (qsl << 4)) ^ ((qr & 7) << 4);
  int ql2 = (((qr + 64) << 8) + (qsl << 4)) ^ ((qr & 7) << 4);
  int ql3 = (((qr + 96) << 8) + (qsl << 4)) ^ ((qr & 7) << 4);
  const f16* qb = qp + ((size_t)b * 8192 + i * 512) * 128;
  // prefetch sc=0 Q tile
  float4 q0 = *(const float4*)(qb + (size_t)(qr      ) * 128 + qsl * 8);
  float4 q1 = *(const float4*)(qb + (size_t)(qr +  32) * 128 + qsl * 8);
  float4 q2 = *(const float4*)(qb + (size_t)(qr +  64) * 128 + qsl * 8);
  float4 q3 = *(const float4*)(qb + (size_t)(qr +  96) * 128 + qsl * 8);
  float zp[2][4] = {{0.f,0.f,0.f,0.f},{0.f,0.f,0.f,0.f}};
  floatx4 zero = {0.f, 0.f, 0.f, 0.f};
  for (int sc = 0; sc < 4; sc++) {
    __syncthreads();                 // prev GEMM reads of sQ done (sc=0: K staged)
    *(float4*)((char*)sQ + ql0) = q0;
    *(float4*)((char*)sQ + ql1) = q1;
    *(float4*)((char*)sQ + ql2) = q2;
    *(float4*)((char*)sQ + ql3) = q3;
    __syncthreads();
    if (sc < 3) {                    // prefetch next chunk during compute
      const f16* qn = qb + (size_t)(sc + 1) * 128 * 128;
      q0 = *(const float4*)(qn + (size_t)(qr      ) * 128 + qsl * 8);
      q1 = *(const float4*)(qn + (size_t)(qr +  32) * 128 + qsl * 8);
      q2 = *(const float4*)(qn + (size_t)(qr +  64) * 128 + qsl * 8);
      q3 = *(const float4*)(qn + (size_t)(qr +  96) * 128 + qsl * 8);
    }
    floatx4 acc[2][4] = {{zero,zero,zero,zero},{zero,zero,zero,zero}};
    for (int kc = 0; kc < 128; kc += 32) {
      half8 ah[2];
      for (int fm = 0; fm < 2; fm++)
        ah[fm] = fragP256(sK, wm * 32 + fm * 16 + lr, kc + lg * 8);
      for (int fn = 0; fn < 4; fn++) {
        half8 bh = fragP256(sQ, wn * 64 + fn * 16 + lr, kc + lg * 8);
        for (int fm = 0; fm < 2; fm++)
          acc[fm][fn] = MFMA16(ah[fm], bh, acc[fm][fn]);
      }
    }
    for (int fm = 0; fm < 2; fm++) for (int fn = 0; fn < 4; fn++)
      for (int jj = 0; jj < 4; jj++)
        zp[fm][jj] += exp2f(acc[fm][fn][jj] * RSL2E);
  }
  // in-wave butterfly over lr (16 s-columns)
  for (int off = 1; off < 16; off <<= 1)
    for (int fm = 0; fm < 2; fm++) for (int jj = 0; jj < 4; jj++)
      zp[fm][jj] += __shfl_xor(zp[fm][jj], off, 64);
  // cross-wave combine of the two wn halves via LDS
  __syncthreads();
  float* sred = (float*)sQ;      // 256 floats
  if (lr == 0) {
    for (int fm = 0; fm < 2; fm++) for (int jj = 0; jj < 4; jj++) {
      int d = wm * 32 + fm * 16 + lg * 4 + jj;
      sred[wn * 128 + d] = zp[fm][jj];
    }
  }
  __syncthreads();
  if (tid < 128) {
    size_t zb = (((size_t)(b * 16 + i) * 16 + j) * 512) + dchunk * 128;
    Z[zb + tid] = sred[tid] + sred[128 + tid];
  }
}

// ---- pass B (reverted to R12 proven structure; launch_bounds relaxed to (512,2);
//      padded-132 epilogue kept). Full-width tiles, 4 barriers/iter. ----
__global__ __launch_bounds__(512, 2)
void k_passB(const f16* __restrict__ qp, const f16* __restrict__ kp,
             const f16* __restrict__ vT,
             const float* __restrict__ Z, float* __restrict__ Pbuf) {
  int bid = blockIdx.x;
  int wg = ((bid & 7) << 7) | (bid >> 3);   // XCD-aware bijective swizzle (1024 = 8*128)
  int dq = wg & 3, st = (wg >> 2) & 7, i = (wg >> 5) & 15, b = wg >> 9;
  __shared__ __align__(16) char pool[65536];
  f16* sQ  = (f16*)pool;              // [64 s][128 c], 256B pitch, 16 KB
  f16* sKV = (f16*)(pool + 16384);    // [128][128], 256B pitch, 32 KB: K tile, then V tile
  f16* sE  = (f16*)(pool + 49152);    // [64 s][128 d], 256B pitch, 16 KB
  int tid = threadIdx.x, wave = tid >> 6, lane = tid & 63, lg = lane >> 4, lr = lane & 15;
  int w1m = wave >> 1, w1n = wave & 1;    // GEMM1: 4(d) x 2(s)
  int w2m = wave >> 2, w2n = wave & 3;    // GEMM2: 2(s) x 4(c)
  int srow = tid >> 4, sslot = tid & 15;
  int sl0 = (((srow      ) << 8) + (sslot << 4)) ^ ((srow & 7) << 4);
  int sl1 = (((srow +  32) << 8) + (sslot << 4)) ^ ((srow & 7) << 4);
  int sl2 = (((srow +  64) << 8) + (sslot << 4)) ^ ((srow & 7) << 4);
  int sl3 = (((srow +  96) << 8) + (sslot << 4)) ^ ((srow & 7) << 4);
  size_t qrow = (size_t)b * 8192 + i * 512 + st * 64;
  stage_rows128(qp + qrow * 128, 128, sQ, 64, tid, 512);
  floatx4 zero = {0.f, 0.f, 0.f, 0.f};
  floatx4 acc2[2][2] = {{zero, zero}, {zero, zero}};
  const f16* vbase = vT + (size_t)b * 1048576;
  for (int slot = 0; slot < 5; slot++) {
    int j = i - 2 + slot;
    if (j < 0 || j > 15) continue;
    // ---- iteration-start loads (land under B1/B2/K-write latency) ----
    const f16* kb = kp + ((size_t)b * 8192 + j * 512 + dq * 128) * 128;
    float4 k0 = *(const float4*)(kb + (size_t)(srow      ) * 128 + sslot * 8);
    float4 k1 = *(const float4*)(kb + (size_t)(srow +  32) * 128 + sslot * 8);
    float4 k2 = *(const float4*)(kb + (size_t)(srow +  64) * 128 + sslot * 8);
    float4 k3 = *(const float4*)(kb + (size_t)(srow +  96) * 128 + sslot * 8);
    const f16* gv = vbase + (size_t)j * 512 + dq * 128;
    float4 v0 = *(const float4*)(gv + (size_t)(srow      ) * 8192 + sslot * 8);
    float4 v1 = *(const float4*)(gv + (size_t)(srow +  32) * 8192 + sslot * 8);
    float4 v2 = *(const float4*)(gv + (size_t)(srow +  64) * 8192 + sslot * 8);
    float4 v3 = *(const float4*)(gv + (size_t)(srow +  96) * 8192 + sslot * 8);
    float rz[2][4];
    {
      size_t zb = (((size_t)(b * 16 + i) * 16 + j) * 512) + dq * 128;
      #pragma unroll
      for (int fm = 0; fm < 2; fm++)
        #pragma unroll
        for (int jj = 0; jj < 4; jj++)
          rz[fm][jj] = 1.0f / Z[zb + w1m * 32 + fm * 16 + lg * 4 + jj];
    }
    __syncthreads();                 // B1: prev GEMM2 done reading sKV(V)/sE
    *(float4*)((char*)sKV + sl0) = k0;
    *(float4*)((char*)sKV + sl1) = k1;
    *(float4*)((char*)sKV + sl2) = k2;
    *(float4*)((char*)sKV + sl3) = k3;
    __syncthreads();                 // B2: K tile staged
    floatx4 acc1[2][2] = {{zero, zero}, {zero, zero}};
    #pragma unroll
    for (int kc = 0; kc < 128; kc += 32) {
      half8 ah0 = fragP256(sKV, w1m * 32 + lr, kc + lg * 8);
      half8 ah1 = fragP256(sKV, w1m * 32 + 16 + lr, kc + lg * 8);
      #pragma unroll
      for (int fn = 0; fn < 2; fn++) {
        half8 bq = fragP256(sQ, w1n * 32 + fn * 16 + lr, kc + lg * 8);
        acc1[0][fn] = MFMA16(ah0, bq, acc1[0][fn]);
        acc1[1][fn] = MFMA16(ah1, bq, acc1[1][fn]);
      }
    }
    __syncthreads();                 // B3: GEMM1 reads of sKV done
    // all waves: write E' quadrant (packed 4x f16 -> 8B) + stage V tile
    #pragma unroll
    for (int fm = 0; fm < 2; fm++)
      #pragma unroll
      for (int fn = 0; fn < 2; fn++) {
        int s = w1n * 32 + fn * 16 + lr;
        int d0 = w1m * 32 + fm * 16 + lg * 4;
        union { f16 a[4]; float2 u; } pk;
        #pragma unroll
        for (int jj = 0; jj < 4; jj++)
          pk.a[jj] = (f16)(exp2f(acc1[fm][fn][jj] * RSL2E) * rz[fm][jj]);
        int ofs = ((s << 8) + (d0 << 1)) ^ ((s & 7) << 4);
        *(float2*)((char*)sE + ofs) = pk.u;
      }
    *(float4*)((char*)sKV + sl0) = v0;
    *(float4*)((char*)sKV + sl1) = v1;
    *(float4*)((char*)sKV + sl2) = v2;
    *(float4*)((char*)sKV + sl3) = v3;
    __syncthreads();                 // B4: E + V staged
    #pragma unroll
    for (int kc = 0; kc < 128; kc += 32) {
      half8 ea0 = fragP256(sE, w2m * 32 + lr, kc + lg * 8);
      half8 ea1 = fragP256(sE, w2m * 32 + 16 + lr, kc + lg * 8);
      #pragma unroll
      for (int fn = 0; fn < 2; fn++) {
        half8 bh = fragP256(sKV, w2n * 32 + fn * 16 + lr, kc + lg * 8);
        acc2[0][fn] = MFMA16(ea0, bh, acc2[0][fn]);
        acc2[1][fn] = MFMA16(ea1, bh, acc2[1][fn]);
      }
    }
  }
  // epilogue: write f32 partial to Pbuf via LDS for coalescing (padded stride 132)
  __syncthreads();
  float* ef = (float*)pool;   // [64][132] f32
  for (int fm = 0; fm < 2; fm++) for (int fn = 0; fn < 2; fn++) {
    int c = w2n * 32 + fn * 16 + lr;
    for (int jj = 0; jj < 4; jj++) {
      int s = w2m * 32 + fm * 16 + lg * 4 + jj;
      ef[s * 132 + c] = acc2[fm][fn][jj];
    }
  }
  __syncthreads();
  float* po = Pbuf + ((size_t)((((b * 16 + i) * 8 + st) * 4) + dq)) * 8192;
  for (int idx = tid; idx < 2048; idx += 512) {
    int r = idx >> 5, sl = idx & 31;
    *(float4*)(po + r * 128 + sl * 4) = *(const float4*)(ef + r * 132 + sl * 4);
  }
}

extern "C" void kernel_launch(void* const* d_in, const int* in_sizes, int n_in,
                              void* d_out, int out_size, void* d_ws, size_t ws_size,
                              hipStream_t stream) {
  const float* query     = (const float*)d_in[0];
  const float* key_value = (const float*)d_in[1];
  const float* Wq  = (const float*)d_in[2];
  const float* bq  = (const float*)d_in[3];
  const float* Wkv = (const float*)d_in[4];
  const float* bkv = (const float*)d_in[5];
  const float* Wo  = (const float*)d_in[6];
  const float* bo  = (const float*)d_in[7];
  float* out = (float*)d_out;

  char* ws = (char*)d_ws;
  size_t off = 0;
  auto alloc = [&](size_t bytes) -> char* {
    char* p = ws + off;
    off += (bytes + 255) & ~(size_t)255;
    return p;
  };
  const size_t SZH = (size_t)16384 * 128 * 2;   // one f16 array over all rows
  f16* qhp  = (f16*)alloc(SZH);   // q projected, single f16
  f16* khp  = (f16*)alloc(SZH);   // k projected, single f16
  f16* vT   = (f16*)alloc(SZH);   // v projected, transposed [b][c][l], single f16
  float* Pbuf = (float*)alloc((size_t)1024 * 8192 * 4);   // 33.5 MB partials (4 d-quarters)
  f16* WqTh  = (f16*)alloc(32768); f16* WqTl  = (f16*)alloc(32768);
  f16* WkvTh = (f16*)alloc(65536); f16* WkvTl = (f16*)alloc(65536);
  f16* WoTh  = (f16*)alloc(32768); f16* WoTl  = (f16*)alloc(32768);
  float* Zb = (float*)alloc((size_t)2 * 16 * 16 * 512 * 4);
  float* Ub = (float*)alloc((size_t)2 * 16 * 128 * 4);
  if (off > ws_size) return;   // workspace too small: bail

  k_splitW<<<256, 256, 0, stream>>>(Wq, Wkv, Wo, WqTh, WqTl, WkvTh, WkvTl, WoTh, WoTl);
  k_proj<<<768, 512, 0, stream>>>(query, key_value, WqTh, WqTl, WkvTh, WkvTl,
                                  bq, bkv, qhp, khp, vT);
  k_U<<<256, 256, 0, stream>>>(vT, Ub);
  k_passA<<<640, 512, 0, stream>>>(khp, qhp, Zb);
  k_passB<<<1024, 512, 0, stream>>>(qhp, khp, vT, Zb, Pbuf);
  k_final<<<256, 512, 0, stream>>>(Pbuf, Ub, WoTh, WoTl, bo, out);
}

// Round 16
// 106.072 us; speedup vs baseline: 1.3595x; 1.1210x over previous
//
#include <hip/hip_runtime.h>

typedef _Float16 f16;
typedef _Float16 half8 __attribute__((ext_vector_type(8)));
typedef float floatx4 __attribute__((ext_vector_type(4)));

#define MFMA16(a,b,c) __builtin_amdgcn_mfma_f32_16x16x32_f16((a),(b),(c),0,0,0)
// (1/sqrt(128)) * log2(e)
#define RSL2E 0.12751743f

__device__ __forceinline__ void split2(float x, f16 &h, f16 &l) {
  f16 hh = (f16)x;
  h = hh;
  l = (f16)(x - (float)hh);
}

// ---- LDS staging: rows of 64 halves (128B pitch), XOR-swizzled ----
__device__ __forceinline__ void stage_rows64(const f16* __restrict__ g, int gstride,
                                             f16* lds, int rows, int tid, int nthr) {
  int total = rows * 8;
  for (int idx = tid; idx < total; idx += nthr) {
    int row = idx >> 3, slot = idx & 7;
    float4 v = *(const float4*)(g + (size_t)row * gstride + slot * 8);
    int lofs = ((row << 7) + (slot << 4)) ^ ((row & 7) << 4);
    *(float4*)((char*)lds + lofs) = v;
  }
}
// rows of 128 halves (256B pitch), XOR-swizzled
__device__ __forceinline__ void stage_rows128(const f16* __restrict__ g, int gstride,
                                              f16* lds, int rows, int tid, int nthr) {
  int total = rows * 16;
  for (int idx = tid; idx < total; idx += nthr) {
    int row = idx >> 4, slot = idx & 15;
    float4 v = *(const float4*)(g + (size_t)row * gstride + slot * 8);
    int lofs = ((row << 8) + (slot << 4)) ^ ((row & 7) << 4);
    *(float4*)((char*)lds + lofs) = v;
  }
}
__device__ __forceinline__ half8 fragP128(const f16* lds, int row, int kofs) {
  int ofs = ((row << 7) + (kofs << 1)) ^ ((row & 7) << 4);
  return *(const half8*)((const char*)lds + ofs);
}
__device__ __forceinline__ half8 fragP256(const f16* lds, int row, int kofs) {
  int ofs = ((row << 8) + (kofs << 1)) ^ ((row & 7) << 4);
  return *(const half8*)((const char*)lds + ofs);
}
// pack a float4 into split h/l uint2 pairs
__device__ __forceinline__ void pack_split(float4 v, uint2 &h, uint2 &l) {
  union { f16 a[4]; uint2 u; } hh, ll;
  split2(v.x, hh.a[0], ll.a[0]);
  split2(v.y, hh.a[1], ll.a[1]);
  split2(v.z, hh.a[2], ll.a[2]);
  split2(v.w, hh.a[3], ll.a[3]);
  h = hh.u; l = ll.u;
}

// ---- transpose + split the three weight matrices ----
__global__ void k_splitW(const float* __restrict__ Wq, const float* __restrict__ Wkv,
                         const float* __restrict__ Wo,
                         f16* WqTh, f16* WqTl, f16* WkvTh, f16* WkvTl,
                         f16* WoTh, f16* WoTl) {
  int idx = blockIdx.x * 256 + threadIdx.x;
  if (idx >= 65536) return;
  float v; f16 *ph, *pl; int dst;
  if (idx < 16384) {
    int n = idx >> 7, c = idx & 127;
    v = Wq[c * 128 + n]; ph = WqTh; pl = WqTl; dst = idx;
  } else if (idx < 49152) {
    int t = idx - 16384; int n = t >> 7, c = t & 127;
    v = Wkv[c * 256 + n]; ph = WkvTh; pl = WkvTl; dst = t;
  } else {
    int t = idx - 49152; int n = t >> 7, c = t & 127;
    v = Wo[c * 128 + n]; ph = WoTh; pl = WoTl; dst = t;
  }
  f16 h, l; split2(v, h, l);
  ph[dst] = h; pl[dst] = l;
}

// ---- fused split+GEMM for all three projections in ONE dispatch (grid 768) ----
// with register prefetch of the cc=64 staging inputs (R11 technique)
__global__ __launch_bounds__(512, 2)
void k_proj(const float* __restrict__ query, const float* __restrict__ key_value,
            const f16* __restrict__ WqTh, const f16* __restrict__ WqTl,
            const f16* __restrict__ WkvTh, const f16* __restrict__ WkvTl,
            const float* __restrict__ bq, const float* __restrict__ bkv,
            f16* __restrict__ qhp, f16* __restrict__ khp, f16* __restrict__ vT) {
  int pidx = blockIdx.x >> 8, blk = blockIdx.x & 255;
  const float* A; const f16 *BTh, *BTl; const float* bias; f16* out; int mode;
  if (pidx == 0)      { A = query;     BTh = WqTh;          BTl = WqTl;          bias = bq;        out = qhp; mode = 0; }
  else if (pidx == 1) { A = key_value; BTh = WkvTh;         BTl = WkvTl;         bias = bkv;       out = khp; mode = 0; }
  else                { A = key_value; BTh = WkvTh + 16384; BTl = WkvTl + 16384; bias = bkv + 128; out = vT;  mode = 1; }
  __shared__ f16 pool[24576];
  f16* sAh = pool;           // [64][64]
  f16* sAl = pool + 4096;
  f16* sBh = pool + 8192;    // [128][64]
  f16* sBl = pool + 16384;
  int tid = threadIdx.x, wave = tid >> 6, lane = tid & 63, lg = lane >> 4, lr = lane & 15;
  int wm = wave >> 2, wn = wave & 3;   // 2 x 4 waves, 32x32 wave tiles
  size_t rowbase = (size_t)blk * 64;
  // staging duties
  int arow = tid >> 4, acg = tid & 15;   // A rows arow, arow+32 (fp32, split on write)
  int al0 = ((arow << 7) + (acg << 3)) ^ ((arow & 7) << 4);
  int al1 = (((arow + 32) << 7) + (acg << 3)) ^ ((arow & 7) << 4);
  int brow = tid >> 3, bslot = tid & 7;  // B rows brow, brow+64
  int bl0 = ((brow << 7) + (bslot << 4)) ^ ((brow & 7) << 4);
  int bl1 = (((brow + 64) << 7) + (bslot << 4)) ^ ((brow & 7) << 4);
  const float* Ab = A + rowbase * 128;
  // prefetch cc=0 inputs
  float4 a0 = *(const float4*)(Ab + (size_t)arow * 128 + acg * 4);
  float4 a1 = *(const float4*)(Ab + (size_t)(arow + 32) * 128 + acg * 4);
  float4 b0h = *(const float4*)(BTh + brow * 128 + bslot * 8);
  float4 b1h = *(const float4*)(BTh + (brow + 64) * 128 + bslot * 8);
  float4 b0l = *(const float4*)(BTl + brow * 128 + bslot * 8);
  float4 b1l = *(const float4*)(BTl + (brow + 64) * 128 + bslot * 8);
  floatx4 zero = {0.f, 0.f, 0.f, 0.f};
  floatx4 acc[2][2] = {{zero, zero}, {zero, zero}};
  #pragma unroll
  for (int cc = 0; cc < 128; cc += 64) {
    __syncthreads();
    {
      uint2 h, l;
      pack_split(a0, h, l);
      *(uint2*)((char*)sAh + al0) = h; *(uint2*)((char*)sAl + al0) = l;
      pack_split(a1, h, l);
      *(uint2*)((char*)sAh + al1) = h; *(uint2*)((char*)sAl + al1) = l;
    }
    *(float4*)((char*)sBh + bl0) = b0h;
    *(float4*)((char*)sBh + bl1) = b1h;
    *(float4*)((char*)sBl + bl0) = b0l;
    *(float4*)((char*)sBl + bl1) = b1l;
    __syncthreads();
    if (cc == 0) {   // prefetch cc=64 inputs during compute
      a0 = *(const float4*)(Ab + (size_t)arow * 128 + 64 + acg * 4);
      a1 = *(const float4*)(Ab + (size_t)(arow + 32) * 128 + 64 + acg * 4);
      b0h = *(const float4*)(BTh + 64 + brow * 128 + bslot * 8);
      b1h = *(const float4*)(BTh + 64 + (brow + 64) * 128 + bslot * 8);
      b0l = *(const float4*)(BTl + 64 + brow * 128 + bslot * 8);
      b1l = *(const float4*)(BTl + 64 + (brow + 64) * 128 + bslot * 8);
    }
    #pragma unroll
    for (int kc = 0; kc < 64; kc += 32) {
      half8 ah[2], al[2];
      for (int fm = 0; fm < 2; fm++) {
        ah[fm] = fragP128(sAh, wm * 32 + fm * 16 + lr, kc + lg * 8);
        al[fm] = fragP128(sAl, wm * 32 + fm * 16 + lr, kc + lg * 8);
      }
      for (int fn = 0; fn < 2; fn++) {
        half8 bh = fragP128(sBh, wn * 32 + fn * 16 + lr, kc + lg * 8);
        half8 bl = fragP128(sBl, wn * 32 + fn * 16 + lr, kc + lg * 8);
        for (int fm = 0; fm < 2; fm++) {
          acc[fm][fn] = MFMA16(ah[fm], bh, acc[fm][fn]);
          acc[fm][fn] = MFMA16(ah[fm], bl, acc[fm][fn]);
          acc[fm][fn] = MFMA16(al[fm], bh, acc[fm][fn]);
        }
      }
    }
  }
  __syncthreads();
  f16* e = pool;          // [64][136] padded, single
  for (int fm = 0; fm < 2; fm++) for (int fn = 0; fn < 2; fn++) {
    int n = wn * 32 + fn * 16 + lr;
    float bs = bias[n];
    for (int jj = 0; jj < 4; jj++) {
      int m = wm * 32 + fm * 16 + lg * 4 + jj;
      e[m * 136 + n] = (f16)(acc[fm][fn][jj] + bs);
    }
  }
  __syncthreads();
  if (mode == 0) {
    for (int idx = tid; idx < 1024; idx += 512) {
      int r = idx >> 4, sl = idx & 15;
      *(float4*)(out + (rowbase + r) * 128 + sl * 8) =
          *(const float4*)((const char*)e + r * 272 + sl * 16);
    }
  } else {
    size_t bidx = rowbase >> 13, lofs = rowbase & 8191;
    for (int idx = tid; idx < 1024; idx += 512) {
      int c = idx >> 3, sl = idx & 7;
      union { f16 a[8]; float4 v; } th;
      for (int t = 0; t < 8; t++) th.a[t] = e[(sl * 8 + t) * 136 + c];
      *(float4*)(out + (bidx * 128 + c) * 8192 + lofs + sl * 8) = th.v;
    }
  }
}

// ---- fused reduce+final projection: out fp32 = (P0+P1+P2+P3+U) * WoT^T + bo ----
// with register prefetch of the cc=64 staging inputs
__global__ __launch_bounds__(512, 2)
void k_final(const float* __restrict__ Pbuf, const float* __restrict__ U,
             const f16* __restrict__ BTh, const f16* __restrict__ BTl,
             const float* __restrict__ bias, float* __restrict__ out) {
  __shared__ f16 pool[24576];
  f16* sAh = pool;
  f16* sAl = pool + 4096;
  f16* sBh = pool + 8192;
  f16* sBl = pool + 16384;
  int tid = threadIdx.x, wave = tid >> 6, lane = tid & 63, lg = lane >> 4, lr = lane & 15;
  int wm = wave >> 2, wn = wave & 3;
  size_t rowbase = (size_t)blockIdx.x * 64;
  int b = (int)(rowbase >> 13), r0 = (int)(rowbase & 8191);
  int i = r0 >> 9, st = (r0 >> 6) & 7;
  const float* p0 = Pbuf + ((size_t)(((b * 16 + i) * 8 + st) * 4)) * 8192;
  const float* p1 = p0 + 8192;
  const float* p2 = p0 + 16384;
  const float* p3 = p0 + 24576;
  const float* Ub = U + ((size_t)b * 16 + i) * 128;
  // staging duties
  int arow = tid >> 4, acg = tid & 15;   // A rows arow, arow+32
  int al0 = ((arow << 7) + (acg << 3)) ^ ((arow & 7) << 4);
  int al1 = (((arow + 32) << 7) + (acg << 3)) ^ ((arow & 7) << 4);
  int brow = tid >> 3, bslot = tid & 7;
  int bl0 = ((brow << 7) + (bslot << 4)) ^ ((brow & 7) << 4);
  int bl1 = (((brow + 64) << 7) + (bslot << 4)) ^ ((brow & 7) << 4);
  // prefetch cc=0 inputs
  int c0 = acg * 4;
  float4 r0a0 = *(const float4*)(p0 + arow * 128 + c0);
  float4 r0a1 = *(const float4*)(p1 + arow * 128 + c0);
  float4 r0a2 = *(const float4*)(p2 + arow * 128 + c0);
  float4 r0a3 = *(const float4*)(p3 + arow * 128 + c0);
  float4 r1a0 = *(const float4*)(p0 + (arow + 32) * 128 + c0);
  float4 r1a1 = *(const float4*)(p1 + (arow + 32) * 128 + c0);
  float4 r1a2 = *(const float4*)(p2 + (arow + 32) * 128 + c0);
  float4 r1a3 = *(const float4*)(p3 + (arow + 32) * 128 + c0);
  float4 uu = *(const float4*)(Ub + c0);
  float4 b0h = *(const float4*)(BTh + brow * 128 + bslot * 8);
  float4 b1h = *(const float4*)(BTh + (brow + 64) * 128 + bslot * 8);
  float4 b0l = *(const float4*)(BTl + brow * 128 + bslot * 8);
  float4 b1l = *(const float4*)(BTl + (brow + 64) * 128 + bslot * 8);
  floatx4 zero = {0.f, 0.f, 0.f, 0.f};
  floatx4 acc[2][2] = {{zero, zero}, {zero, zero}};
  #pragma unroll
  for (int cc = 0; cc < 128; cc += 64) {
    __syncthreads();
    {
      float4 s0, s1;
      s0.x = (r0a0.x + r0a1.x) + (r0a2.x + r0a3.x) + uu.x;
      s0.y = (r0a0.y + r0a1.y) + (r0a2.y + r0a3.y) + uu.y;
      s0.z = (r0a0.z + r0a1.z) + (r0a2.z + r0a3.z) + uu.z;
      s0.w = (r0a0.w + r0a1.w) + (r0a2.w + r0a3.w) + uu.w;
      s1.x = (r1a0.x + r1a1.x) + (r1a2.x + r1a3.x) + uu.x;
      s1.y = (r1a0.y + r1a1.y) + (r1a2.y + r1a3.y) + uu.y;
      s1.z = (r1a0.z + r1a1.z) + (r1a2.z + r1a3.z) + uu.z;
      s1.w = (r1a0.w + r1a1.w) + (r1a2.w + r1a3.w) + uu.w;
      uint2 h, l;
      pack_split(s0, h, l);
      *(uint2*)((char*)sAh + al0) = h; *(uint2*)((char*)sAl + al0) = l;
      pack_split(s1, h, l);
      *(uint2*)((char*)sAh + al1) = h; *(uint2*)((char*)sAl + al1) = l;
    }
    *(float4*)((char*)sBh + bl0) = b0h;
    *(float4*)((char*)sBh + bl1) = b1h;
    *(float4*)((char*)sBl + bl0) = b0l;
    *(float4*)((char*)sBl + bl1) = b1l;
    __syncthreads();
    if (cc == 0) {   // prefetch cc=64 inputs during compute
      int c1 = 64 + acg * 4;
      r0a0 = *(const float4*)(p0 + arow * 128 + c1);
      r0a1 = *(const float4*)(p1 + arow * 128 + c1);
      r0a2 = *(const float4*)(p2 + arow * 128 + c1);
      r0a3 = *(const float4*)(p3 + arow * 128 + c1);
      r1a0 = *(const float4*)(p0 + (arow + 32) * 128 + c1);
      r1a1 = *(const float4*)(p1 + (arow + 32) * 128 + c1);
      r1a2 = *(const float4*)(p2 + (arow + 32) * 128 + c1);
      r1a3 = *(const float4*)(p3 + (arow + 32) * 128 + c1);
      uu   = *(const float4*)(Ub + c1);
      b0h = *(const float4*)(BTh + 64 + brow * 128 + bslot * 8);
      b1h = *(const float4*)(BTh + 64 + (brow + 64) * 128 + bslot * 8);
      b0l = *(const float4*)(BTl + 64 + brow * 128 + bslot * 8);
      b1l = *(const float4*)(BTl + 64 + (brow + 64) * 128 + bslot * 8);
    }
    #pragma unroll
    for (int kc = 0; kc < 64; kc += 32) {
      half8 ah[2], al[2];
      for (int fm = 0; fm < 2; fm++) {
        ah[fm] = fragP128(sAh, wm * 32 + fm * 16 + lr, kc + lg * 8);
        al[fm] = fragP128(sAl, wm * 32 + fm * 16 + lr, kc + lg * 8);
      }
      for (int fn = 0; fn < 2; fn++) {
        half8 bh = fragP128(sBh, wn * 32 + fn * 16 + lr, kc + lg * 8);
        half8 bl = fragP128(sBl, wn * 32 + fn * 16 + lr, kc + lg * 8);
        for (int fm = 0; fm < 2; fm++) {
          acc[fm][fn] = MFMA16(ah[fm], bh, acc[fm][fn]);
          acc[fm][fn] = MFMA16(ah[fm], bl, acc[fm][fn]);
          acc[fm][fn] = MFMA16(al[fm], bh, acc[fm][fn]);
        }
      }
    }
  }
  __syncthreads();
  float* ef = (float*)pool;   // [64][132] padded fp32
  for (int fm = 0; fm < 2; fm++) for (int fn = 0; fn < 2; fn++) {
    int n = wn * 32 + fn * 16 + lr;
    float bs = bias[n];
    for (int jj = 0; jj < 4; jj++) {
      int m = wm * 32 + fm * 16 + lg * 4 + jj;
      ef[m * 132 + n] = acc[fm][fn][jj] + bs;
    }
  }
  __syncthreads();
  for (int idx = tid; idx < 2048; idx += 512) {
    int r = idx >> 5, sl = idx & 31;
    *(float4*)(out + (rowbase + r) * 128 + sl * 4) = *(const float4*)(ef + r * 132 + sl * 4);
  }
}

// ---- U[b][i][c] = (1/512) * sum over disallowed k-blocks of their column sums of v ----
__global__ void k_U(const f16* __restrict__ vT, float* __restrict__ U) {
  int b = blockIdx.x >> 7, c = blockIdx.x & 127;
  int tid = threadIdx.x;
  const f16* r = vT + ((size_t)b * 128 + c) * 8192;
  float s = 0.f;
  const float4* r4 = (const float4*)(r + tid * 32);
  for (int t = 0; t < 4; t++) {
    float4 v = r4[t];
    const f16* a = (const f16*)&v;
    for (int u = 0; u < 8; u++) s += (float)a[u];
  }
  __shared__ float part[256];
  __shared__ float bs[16];
  part[tid] = s;
  __syncthreads();
  if (tid < 16) {
    float t = 0.f;
    for (int u = 0; u < 16; u++) t += part[tid * 16 + u];
    bs[tid] = t;
  }
  __syncthreads();
  if (tid < 16) {
    int i = tid;
    float tot = 0.f;
    for (int j = 0; j < 16; j++) tot += bs[j];
    int j0 = i - 2 < 0 ? 0 : i - 2;
    int j1 = i + 2 > 15 ? 15 : i + 2;
    float win = 0.f;
    for (int j = j0; j <= j1; j++) win += bs[j];
    U[((size_t)b * 16 + i) * 128 + c] = (tot - win) * (1.0f / 512.0f);
  }
}

// ---- pass A: Z[b][i][j][d] = sum_s exp2(RSL2E * (k_d . q_s)) ----
// with register prefetch of the next sc-chunk's Q tile
__global__ __launch_bounds__(512, 4)
void k_passA(const f16* __restrict__ kp, const f16* __restrict__ qp,
             float* __restrict__ Z) {
  int bid = blockIdx.x;
  int wg = (bid & 7) * 80 + (bid >> 3);     // XCD-aware bijective swizzle (640 = 8*80)
  int dchunk = wg & 3; int rest = wg >> 2;
  int slot = rest % 5; int rest2 = rest / 5;
  int i = rest2 & 15; int b = rest2 >> 4;
  int j = i - 2 + slot;
  if (j < 0 || j > 15) return;
  __shared__ f16 sK[16384], sQ[16384];  // 64 KiB -> 2 WG/CU
  int tid = threadIdx.x, wave = tid >> 6, lane = tid & 63, lg = lane >> 4, lr = lane & 15;
  int wm = wave >> 1, wn = wave & 1;   // 4 x 2 waves; wave tile 32(d) x 64(s)
  size_t krow = (size_t)b * 8192 + j * 512 + dchunk * 128;
  stage_rows128(kp + krow * 128, 128, sK, 128, tid, 512);
  // Q staging duty: rows qr, qr+32, qr+64, qr+96; 16B slot qsl
  int qr = tid >> 4, qsl = tid & 15;
  int ql0 = ((qr << 8) + (qsl << 4)) ^ ((qr & 7) << 4);
  int ql1 = (((qr + 32) << 8) + (qsl << 4)) ^ ((qr & 7) << 4);
  int ql2 = (((qr + 64) << 8) + (qsl << 4)) ^ ((qr & 7) << 4);
  int ql3 = (((qr + 96) << 8) + (qsl << 4)) ^ ((qr & 7) << 4);
  const f16* qb = qp + ((size_t)b * 8192 + i * 512) * 128;
  // prefetch sc=0 Q tile
  float4 q0 = *(const float4*)(qb + (size_t)(qr      ) * 128 + qsl * 8);
  float4 q1 = *(const float4*)(qb + (size_t)(qr +  32) * 128 + qsl * 8);
  float4 q2 = *(const float4*)(qb + (size_t)(qr +  64) * 128 + qsl * 8);
  float4 q3 = *(const float4*)(qb + (size_t)(qr +  96) * 128 + qsl * 8);
  float zp[2][4] = {{0.f,0.f,0.f,0.f},{0.f,0.f,0.f,0.f}};
  floatx4 zero = {0.f, 0.f, 0.f, 0.f};
  for (int sc = 0; sc < 4; sc++) {
    __syncthreads();                 // prev GEMM reads of sQ done (sc=0: K staged)
    *(float4*)((char*)sQ + ql0) = q0;
    *(float4*)((char*)sQ + ql1) = q1;
    *(float4*)((char*)sQ + ql2) = q2;
    *(float4*)((char*)sQ + ql3) = q3;
    __syncthreads();
    if (sc < 3) {                    // prefetch next chunk during compute
      const f16* qn = qb + (size_t)(sc + 1) * 128 * 128;
      q0 = *(const float4*)(qn + (size_t)(qr      ) * 128 + qsl * 8);
      q1 = *(const float4*)(qn + (size_t)(qr +  32) * 128 + qsl * 8);
      q2 = *(const float4*)(qn + (size_t)(qr +  64) * 128 + qsl * 8);
      q3 = *(const float4*)(qn + (size_t)(qr +  96) * 128 + qsl * 8);
    }
    floatx4 acc[2][4] = {{zero,zero,zero,zero},{zero,zero,zero,zero}};
    for (int kc = 0; kc < 128; kc += 32) {
      half8 ah[2];
      for (int fm = 0; fm < 2; fm++)
        ah[fm] = fragP256(sK, wm * 32 + fm * 16 + lr, kc + lg * 8);
      for (int fn = 0; fn < 4; fn++) {
        half8 bh = fragP256(sQ, wn * 64 + fn * 16 + lr, kc + lg * 8);
        for (int fm = 0; fm < 2; fm++)
          acc[fm][fn] = MFMA16(ah[fm], bh, acc[fm][fn]);
      }
    }
    for (int fm = 0; fm < 2; fm++) for (int fn = 0; fn < 4; fn++)
      for (int jj = 0; jj < 4; jj++)
        zp[fm][jj] += exp2f(acc[fm][fn][jj] * RSL2E);
  }
  // in-wave butterfly over lr (16 s-columns)
  for (int off = 1; off < 16; off <<= 1)
    for (int fm = 0; fm < 2; fm++) for (int jj = 0; jj < 4; jj++)
      zp[fm][jj] += __shfl_xor(zp[fm][jj], off, 64);
  // cross-wave combine of the two wn halves via LDS
  __syncthreads();
  float* sred = (float*)sQ;      // 256 floats
  if (lr == 0) {
    for (int fm = 0; fm < 2; fm++) for (int jj = 0; jj < 4; jj++) {
      int d = wm * 32 + fm * 16 + lg * 4 + jj;
      sred[wn * 128 + d] = zp[fm][jj];
    }
  }
  __syncthreads();
  if (tid < 128) {
    size_t zb = (((size_t)(b * 16 + i) * 16 + j) * 512) + dchunk * 128;
    Z[zb + tid] = sred[tid] + sred[128 + tid];
  }
}

// ---- pass B (R13 best config): full-width tiles, 4 barriers/iter,
//      iteration-start loads, launch_bounds(512,4) ----
__global__ __launch_bounds__(512, 4)
void k_passB(const f16* __restrict__ qp, const f16* __restrict__ kp,
             const f16* __restrict__ vT,
             const float* __restrict__ Z, float* __restrict__ Pbuf) {
  int bid = blockIdx.x;
  int wg = ((bid & 7) << 7) | (bid >> 3);   // XCD-aware bijective swizzle (1024 = 8*128)
  int dq = wg & 3, st = (wg >> 2) & 7, i = (wg >> 5) & 15, b = wg >> 9;
  __shared__ __align__(16) char pool[65536];
  f16* sQ  = (f16*)pool;              // [64 s][128 c], 256B pitch, 16 KB
  f16* sKV = (f16*)(pool + 16384);    // [128][128], 256B pitch, 32 KB: K tile, then V tile
  f16* sE  = (f16*)(pool + 49152);    // [64 s][128 d], 256B pitch, 16 KB
  int tid = threadIdx.x, wave = tid >> 6, lane = tid & 63, lg = lane >> 4, lr = lane & 15;
  int w1m = wave >> 1, w1n = wave & 1;    // GEMM1: 4(d) x 2(s)
  int w2m = wave >> 2, w2n = wave & 3;    // GEMM2: 2(s) x 4(c)
  int srow = tid >> 4, sslot = tid & 15;
  int sl0 = (((srow      ) << 8) + (sslot << 4)) ^ ((srow & 7) << 4);
  int sl1 = (((srow +  32) << 8) + (sslot << 4)) ^ ((srow & 7) << 4);
  int sl2 = (((srow +  64) << 8) + (sslot << 4)) ^ ((srow & 7) << 4);
  int sl3 = (((srow +  96) << 8) + (sslot << 4)) ^ ((srow & 7) << 4);
  size_t qrow = (size_t)b * 8192 + i * 512 + st * 64;
  stage_rows128(qp + qrow * 128, 128, sQ, 64, tid, 512);
  floatx4 zero = {0.f, 0.f, 0.f, 0.f};
  floatx4 acc2[2][2] = {{zero, zero}, {zero, zero}};
  const f16* vbase = vT + (size_t)b * 1048576;
  for (int slot = 0; slot < 5; slot++) {
    int j = i - 2 + slot;
    if (j < 0 || j > 15) continue;
    // ---- iteration-start loads ----
    const f16* kb = kp + ((size_t)b * 8192 + j * 512 + dq * 128) * 128;
    float4 k0 = *(const float4*)(kb + (size_t)(srow      ) * 128 + sslot * 8);
    float4 k1 = *(const float4*)(kb + (size_t)(srow +  32) * 128 + sslot * 8);
    float4 k2 = *(const float4*)(kb + (size_t)(srow +  64) * 128 + sslot * 8);
    float4 k3 = *(const float4*)(kb + (size_t)(srow +  96) * 128 + sslot * 8);
    const f16* gv = vbase + (size_t)j * 512 + dq * 128;
    float4 v0 = *(const float4*)(gv + (size_t)(srow      ) * 8192 + sslot * 8);
    float4 v1 = *(const float4*)(gv + (size_t)(srow +  32) * 8192 + sslot * 8);
    float4 v2 = *(const float4*)(gv + (size_t)(srow +  64) * 8192 + sslot * 8);
    float4 v3 = *(const float4*)(gv + (size_t)(srow +  96) * 8192 + sslot * 8);
    float rz[2][4];
    {
      size_t zb = (((size_t)(b * 16 + i) * 16 + j) * 512) + dq * 128;
      #pragma unroll
      for (int fm = 0; fm < 2; fm++)
        #pragma unroll
        for (int jj = 0; jj < 4; jj++)
          rz[fm][jj] = 1.0f / Z[zb + w1m * 32 + fm * 16 + lg * 4 + jj];
    }
    __syncthreads();                 // B1: prev GEMM2 done reading sKV(V)/sE
    *(float4*)((char*)sKV + sl0) = k0;
    *(float4*)((char*)sKV + sl1) = k1;
    *(float4*)((char*)sKV + sl2) = k2;
    *(float4*)((char*)sKV + sl3) = k3;
    __syncthreads();                 // B2: K tile staged
    floatx4 acc1[2][2] = {{zero, zero}, {zero, zero}};
    #pragma unroll
    for (int kc = 0; kc < 128; kc += 32) {
      half8 ah0 = fragP256(sKV, w1m * 32 + lr, kc + lg * 8);
      half8 ah1 = fragP256(sKV, w1m * 32 + 16 + lr, kc + lg * 8);
      #pragma unroll
      for (int fn = 0; fn < 2; fn++) {
        half8 bq = fragP256(sQ, w1n * 32 + fn * 16 + lr, kc + lg * 8);
        acc1[0][fn] = MFMA16(ah0, bq, acc1[0][fn]);
        acc1[1][fn] = MFMA16(ah1, bq, acc1[1][fn]);
      }
    }
    __syncthreads();                 // B3: GEMM1 reads of sKV done
    // all waves: write E' quadrant (packed 4x f16 -> 8B) + stage V tile
    #pragma unroll
    for (int fm = 0; fm < 2; fm++)
      #pragma unroll
      for (int fn = 0; fn < 2; fn++) {
        int s = w1n * 32 + fn * 16 + lr;
        int d0 = w1m * 32 + fm * 16 + lg * 4;
        union { f16 a[4]; float2 u; } pk;
        #pragma unroll
        for (int jj = 0; jj < 4; jj++)
          pk.a[jj] = (f16)(exp2f(acc1[fm][fn][jj] * RSL2E) * rz[fm][jj]);
        int ofs = ((s << 8) + (d0 << 1)) ^ ((s & 7) << 4);
        *(float2*)((char*)sE + ofs) = pk.u;
      }
    *(float4*)((char*)sKV + sl0) = v0;
    *(float4*)((char*)sKV + sl1) = v1;
    *(float4*)((char*)sKV + sl2) = v2;
    *(float4*)((char*)sKV + sl3) = v3;
    __syncthreads();                 // B4: E + V staged
    #pragma unroll
    for (int kc = 0; kc < 128; kc += 32) {
      half8 ea0 = fragP256(sE, w2m * 32 + lr, kc + lg * 8);
      half8 ea1 = fragP256(sE, w2m * 32 + 16 + lr, kc + lg * 8);
      #pragma unroll
      for (int fn = 0; fn < 2; fn++) {
        half8 bh = fragP256(sKV, w2n * 32 + fn * 16 + lr, kc + lg * 8);
        acc2[0][fn] = MFMA16(ea0, bh, acc2[0][fn]);
        acc2[1][fn] = MFMA16(ea1, bh, acc2[1][fn]);
      }
    }
  }
  // epilogue: write f32 partial to Pbuf via LDS for coalescing
  __syncthreads();
  float* ef = (float*)pool;   // [64][128] f32 = 32 KB
  for (int fm = 0; fm < 2; fm++) for (int fn = 0; fn < 2; fn++) {
    int c = w2n * 32 + fn * 16 + lr;
    for (int jj = 0; jj < 4; jj++) {
      int s = w2m * 32 + fm * 16 + lg * 4 + jj;
      ef[s * 128 + c] = acc2[fm][fn][jj];
    }
  }
  __syncthreads();
  float* po = Pbuf + ((size_t)((((b * 16 + i) * 8 + st) * 4) + dq)) * 8192;
  for (int idx = tid; idx < 2048; idx += 512)
    ((float4*)po)[idx] = ((const float4*)ef)[idx];
}

extern "C" void kernel_launch(void* const* d_in, const int* in_sizes, int n_in,
                              void* d_out, int out_size, void* d_ws, size_t ws_size,
                              hipStream_t stream) {
  const float* query     = (const float*)d_in[0];
  const float* key_value = (const float*)d_in[1];
  const float* Wq  = (const float*)d_in[2];
  const float* bq  = (const float*)d_in[3];
  const float* Wkv = (const float*)d_in[4];
  const float* bkv = (const float*)d_in[5];
  const float* Wo  = (const float*)d_in[6];
  const float* bo  = (const float*)d_in[7];
  float* out = (float*)d_out;

  char* ws = (char*)d_ws;
  size_t off = 0;
  auto alloc = [&](size_t bytes) -> char* {
    char* p = ws + off;
    off += (bytes + 255) & ~(size_t)255;
    return p;
  };
  const size_t SZH = (size_t)16384 * 128 * 2;   // one f16 array over all rows
  f16* qhp  = (f16*)alloc(SZH);   // q projected, single f16
  f16* khp  = (f16*)alloc(SZH);   // k projected, single f16
  f16* vT   = (f16*)alloc(SZH);   // v projected, transposed [b][c][l], single f16
  float* Pbuf = (float*)alloc((size_t)1024 * 8192 * 4);   // 33.5 MB partials (4 d-quarters)
  f16* WqTh  = (f16*)alloc(32768); f16* WqTl  = (f16*)alloc(32768);
  f16* WkvTh = (f16*)alloc(65536); f16* WkvTl = (f16*)alloc(65536);
  f16* WoTh  = (f16*)alloc(32768); f16* WoTl  = (f16*)alloc(32768);
  float* Zb = (float*)alloc((size_t)2 * 16 * 16 * 512 * 4);
  float* Ub = (float*)alloc((size_t)2 * 16 * 128 * 4);
  if (off > ws_size) return;   // workspace too small: bail

  k_splitW<<<256, 256, 0, stream>>>(Wq, Wkv, Wo, WqTh, WqTl, WkvTh, WkvTl, WoTh, WoTl);
  k_proj<<<768, 512, 0, stream>>>(query, key_value, WqTh, WqTl, WkvTh, WkvTl,
                                  bq, bkv, qhp, khp, vT);
  k_U<<<256, 256, 0, stream>>>(vT, Ub);
  k_passA<<<640, 512, 0, stream>>>(khp, qhp, Zb);
  k_passB<<<1024, 512, 0, stream>>>(qhp, khp, vT, Zb, Pbuf);
  k_final<<<256, 512, 0, stream>>>(Pbuf, Ub, WoTh, WoTl, bo, out);
}